// Round 1
// baseline (8249.911 us; speedup 1.0000x reference)
//
#include <hip/hip_runtime.h>
#include <math.h>

typedef float  floatx4  __attribute__((ext_vector_type(4)));
typedef int    intx4    __attribute__((ext_vector_type(4)));
typedef unsigned short ushortx4 __attribute__((ext_vector_type(4)));

// ---------- bf16 helpers (RNE) ----------
__device__ inline unsigned short f2bf(float x){
  unsigned u = __float_as_uint(x);
  u += 0x7FFFu + ((u >> 16) & 1u);
  return (unsigned short)(u >> 16);
}
__device__ inline float bf2f(unsigned short b){
  return __uint_as_float(((unsigned)b) << 16);
}

// ---------- MFMA 16x16x32 bf16 (inline asm, tied acc) ----------
// A-frag: lane l holds A[l&15][(l>>4)*8 + j], j=0..7 (8 bf16 packed in 4 VGPRs)
// B-frag: lane l holds B[(l>>4)*8 + j][l&15]
// C/D   : lane l reg r = D[(l>>4)*4 + r][l&15]
__device__ inline void mfma_bf16(floatx4& acc, intx4 a, intx4 b){
  asm("v_mfma_f32_16x16x32_bf16 %0, %1, %2, %0" : "+v"(acc) : "v"(a), "v"(b));
}

// =======================================================================
// Split-bf16 GEMM:  out[M,N] = A_f32[M,K] @ W_f32[K,N] (+bias)(+res)(gelu)(scatter)
// A,W are split into hi/lo bf16 during LDS staging; 3 MFMAs per frag pair.
// MODE 0: out = acc + bias (f32)
// MODE 1: out = acc + bias + res   (residual; res may alias out)
// MODE 2: out = gelu_exact(acc + bias)
// MODE 3: out[rowmap[row]] = acc + bias   (row scatter)
// =======================================================================
template<int BM, int BN, int MODE>
__global__ __launch_bounds__(256) void gemm_kernel(
    const float* __restrict__ A, const float* __restrict__ W,
    const float* __restrict__ bias, const float* res,
    float* out, const int* __restrict__ rowmap,
    int M, int N, int K)
{
  constexpr int LD = 40;
  __shared__ unsigned short Ahi[BM][LD], Alo[BM][LD], Whi[BN][LD], Wlo[BN][LD];
  const int tid  = threadIdx.x;
  const int lane = tid & 63, wv = tid >> 6;
  const int wm = wv >> 1, wn = wv & 1;
  const int m0 = blockIdx.y * BM, n0 = blockIdx.x * BN;
  constexpr int MR = BM / 32, NR = BN / 32;
  floatx4 acc[MR][NR];
  #pragma unroll
  for (int mr = 0; mr < MR; mr++)
    #pragma unroll
    for (int nr = 0; nr < NR; nr++) acc[mr][nr] = 0.f;

  const int fr = lane & 15, kg = lane >> 4;

  for (int k0 = 0; k0 < K; k0 += 32){
    __syncthreads();
    // ---- stage A tile: BM x 32 f32 -> hi/lo bf16, row-major [row][k], LD=40
    for (int c = tid; c < BM * 8; c += 256){
      int row = c >> 3, ko = (c & 7) << 2;
      floatx4 av = *(const floatx4*)(A + (size_t)(m0 + row) * K + k0 + ko);
      ushortx4 hi, lo;
      #pragma unroll
      for (int j = 0; j < 4; j++){
        unsigned short h = f2bf(av[j]);
        hi[j] = h;
        lo[j] = f2bf(av[j] - bf2f(h));
      }
      *(ushortx4*)&Ahi[row][ko] = hi;
      *(ushortx4*)&Alo[row][ko] = lo;
    }
    // ---- stage W tile: 32 x BN f32 -> transposed LDS [n][k] hi/lo
    // lanes are k-contiguous so the b16 scatter writes are bank-conflict-free
    for (int c = tid; c < BN * 8; c += 256){
      int k = c & 31, n4 = (c >> 5) << 2;
      floatx4 wvv = *(const floatx4*)(W + (size_t)(k0 + k) * N + n0 + n4);
      #pragma unroll
      for (int j = 0; j < 4; j++){
        unsigned short h = f2bf(wvv[j]);
        Whi[n4 + j][k] = h;
        Wlo[n4 + j][k] = f2bf(wvv[j] - bf2f(h));
      }
    }
    __syncthreads();
    // ---- fragments + MFMA
    intx4 ah[MR], al[MR], wh[NR], wl[NR];
    #pragma unroll
    for (int mr = 0; mr < MR; mr++){
      int row = wm * (BM / 2) + mr * 16 + fr;
      ah[mr] = *(const intx4*)&Ahi[row][kg * 8];
      al[mr] = *(const intx4*)&Alo[row][kg * 8];
    }
    #pragma unroll
    for (int nr = 0; nr < NR; nr++){
      int col = wn * (BN / 2) + nr * 16 + fr;
      wh[nr] = *(const intx4*)&Whi[col][kg * 8];
      wl[nr] = *(const intx4*)&Wlo[col][kg * 8];
    }
    #pragma unroll
    for (int mr = 0; mr < MR; mr++)
      #pragma unroll
      for (int nr = 0; nr < NR; nr++){
        mfma_bf16(acc[mr][nr], al[mr], wh[nr]);
        mfma_bf16(acc[mr][nr], ah[mr], wl[nr]);
        mfma_bf16(acc[mr][nr], ah[mr], wh[nr]);
      }
  }
  // MFMA -> VALU read hazard guard
  asm volatile("s_nop 7\n\ts_nop 7" ::: "memory");
  // ---- epilogue
  #pragma unroll
  for (int mr = 0; mr < MR; mr++)
    #pragma unroll
    for (int nr = 0; nr < NR; nr++){
      int col = n0 + wn * (BN / 2) + nr * 16 + fr;
      float bv = bias ? bias[col] : 0.f;
      #pragma unroll
      for (int e = 0; e < 4; e++){
        int row = m0 + wm * (BM / 2) + mr * 16 + kg * 4 + e;
        float v = acc[mr][nr][e] + bv;
        if (MODE == 1) v += res[(size_t)row * N + col];
        if (MODE == 2) v = 0.5f * v * (1.f + erff(v * 0.70710678118654752f));
        size_t orow = (MODE == 3) ? (size_t)rowmap[row] : (size_t)row;
        out[orow * N + col] = v;
      }
    }
}

// =======================================================================
// RMSNorm (f32 in -> f32 out), one block per row
// =======================================================================
__global__ __launch_bounds__(256) void rmsnorm_kernel(
    const float* __restrict__ x, const float* __restrict__ w,
    float* __restrict__ y, int D)
{
  const int row = blockIdx.x;
  const float* xr = x + (size_t)row * D;
  float ss = 0.f;
  for (int i = threadIdx.x; i < D; i += 256){ float v = xr[i]; ss = fmaf(v, v, ss); }
  for (int o = 32; o > 0; o >>= 1) ss += __shfl_down(ss, o);
  __shared__ float wsum[4];
  __shared__ float snorm;
  const int lane = threadIdx.x & 63, wvi = threadIdx.x >> 6;
  if (lane == 0) wsum[wvi] = ss;
  __syncthreads();
  if (threadIdx.x == 0){
    float t = wsum[0] + wsum[1] + wsum[2] + wsum[3];
    snorm = 1.0f / sqrtf(t / (float)D + 1e-6f);
  }
  __syncthreads();
  float s = snorm;
  float* yr = y + (size_t)row * D;
  for (int i = threadIdx.x; i < D; i += 256) yr[i] = xr[i] * s * w[i];
}

// =======================================================================
// Patch preprocess gather (window permutation folded in): X[1024][1184]
// =======================================================================
__global__ __launch_bounds__(256) void gather_x_kernel(
    const float* __restrict__ img, const int* __restrict__ win, float* __restrict__ X)
{
  int idx = blockIdx.x * 256 + threadIdx.x;
  if (idx >= 1024 * 1184) return;
  int s = idx / 1184, f = idx - s * 1184;
  float val = 0.f;
  if (f < 1176){
    int sp = (win[s >> 2] << 2) | (s & 3);        // permuted source token
    int i0 = sp >> 6, r = sp & 63;
    int i3 = r >> 2, rr = r & 3, i1 = rr >> 1, i4 = rr & 1;
    int c  = f / 392, f2 = f - c * 392;
    int f3 = f2 % 196;                            // t (f2/196) duplicates, ignore
    int ph = f3 / 14, pw2 = f3 - ph * 14;
    int hp = (i0 * 2 + i1) * 14 + ph, wp = (i3 * 2 + i4) * 14 + pw2;
    val = img[((size_t)c * 448 + hp) * 448 + wp];
  }
  X[idx] = val;
}

// patch_w padded K 1176 -> 1184 with zero rows
__global__ __launch_bounds__(256) void pad_pw_kernel(
    const float* __restrict__ pw, float* __restrict__ out)
{
  int idx = blockIdx.x * 256 + threadIdx.x;
  if (idx >= 1184 * 1280) return;
  out[idx] = (idx < 1176 * 1280) ? pw[idx] : 0.f;
}

// cos/sin tables (1024 x 80), window permutation folded in
__global__ __launch_bounds__(256) void rope_tables_kernel(
    const float* __restrict__ rpe, const int* __restrict__ win,
    float* __restrict__ cosb, float* __restrict__ sinb)
{
  int idx = blockIdx.x * 256 + threadIdx.x;
  if (idx >= 1024 * 80) return;
  int s = idx / 80, d = idx - s * 80;
  int src = (win[s >> 2] << 2) | (s & 3);
  float ang = rpe[src * 40 + (d % 40)];
  cosb[idx] = cosf(ang);
  sinb[idx] = sinf(ang);
}

// qkv (S,3,16,80) f32 -> rope(q,k), head-major q/k/v (16,1024,80) f32
__global__ __launch_bounds__(256) void rope_apply_kernel(
    const float* __restrict__ qkv, const float* __restrict__ cosb, const float* __restrict__ sinb,
    float* __restrict__ qh, float* __restrict__ kh, float* __restrict__ vh)
{
  int idx = blockIdx.x * 256 + threadIdx.x;
  if (idx >= 1024 * 16 * 80) return;
  int s = idx / 1280, rem = idx - s * 1280;
  int hd = rem / 80, d = rem - hd * 80;
  const float* base = qkv + (size_t)s * 3840;
  float qv = base[hd * 80 + d];
  float kv = base[1280 + hd * 80 + d];
  float vv = base[2560 + hd * 80 + d];
  float qo = (d < 40) ? -base[hd * 80 + d + 40] : base[hd * 80 + d - 40];
  float ko = (d < 40) ? -base[1280 + hd * 80 + d + 40] : base[1280 + hd * 80 + d - 40];
  float cc = cosb[s * 80 + d], sn = sinb[s * 80 + d];
  size_t o = ((size_t)hd * 1024 + s) * 80 + d;
  qh[o] = qv * cc + qo * sn;
  kh[o] = kv * cc + ko * sn;
  vh[o] = vv;
}

// silu(g)*u
__global__ __launch_bounds__(256) void silu_mul_kernel(
    const float* __restrict__ g, const float* __restrict__ u,
    float* __restrict__ d, int n)
{
  int idx = blockIdx.x * 256 + threadIdx.x;
  if (idx >= n) return;
  float gv = g[idx];
  float s = gv / (1.f + __expf(-gv));
  d[idx] = s * u[idx];
}

// =======================================================================
// Attention (f32, flash-style). block = (q-tile of 64, head), 256 threads.
// FULL: iterate all 16 k-tiles; window: only the diagonal tile (exact,
// since exp(-10000+x) underflows to 0 in the reference softmax).
// =======================================================================
template<bool FULL>
__global__ __launch_bounds__(256) void attn_kernel(
    const float* __restrict__ qg, const float* __restrict__ kg,
    const float* __restrict__ vg, float* __restrict__ og)
{
  __shared__ float qs[64][84];
  __shared__ float kvs[64][84];   // holds K during scores, V during PV
  __shared__ float ps[64][68];
  __shared__ float mrow[64], lrow[64], crow[64], psum[64][4];
  const int tid = threadIdx.x;
  const int qb = blockIdx.x, hd = blockIdx.y;
  const float scale = 0.11180339887498949f; // 1/sqrt(80)

  const float* qh = qg + ((size_t)hd * 1024 + qb * 64) * 80;
  for (int c = tid; c < 64 * 20; c += 256){
    int r = c / 20, d4 = (c - r * 20) * 4;
    *(floatx4*)&qs[r][d4] = *(const floatx4*)(qh + r * 80 + d4);
  }
  if (tid < 64){ mrow[tid] = -3e38f; lrow[tid] = 0.f; }
  float oacc[20];
  #pragma unroll
  for (int j = 0; j < 20; j++) oacc[j] = 0.f;

  const int rq = (tid >> 4) * 4, rc = (tid & 15) * 4;
  const int oqi = tid >> 2, od = (tid & 3) * 20;
  const int kb0 = FULL ? 0 : qb, kb1 = FULL ? 16 : qb + 1;

  for (int kb = kb0; kb < kb1; kb++){
    __syncthreads();
    { const float* kh = kg + ((size_t)hd * 1024 + kb * 64) * 80;
      for (int c = tid; c < 64 * 20; c += 256){
        int r = c / 20, d4 = (c - r * 20) * 4;
        *(floatx4*)&kvs[r][d4] = *(const floatx4*)(kh + r * 80 + d4);
      } }
    __syncthreads();
    // ---- scores: 4x4 per thread, register-blocked
    float sc[4][4];
    #pragma unroll
    for (int i = 0; i < 4; i++)
      #pragma unroll
      for (int j = 0; j < 4; j++) sc[i][j] = 0.f;
    for (int dc = 0; dc < 20; dc++){
      floatx4 qv[4], kv[4];
      #pragma unroll
      for (int i = 0; i < 4; i++){
        qv[i] = *(const floatx4*)&qs[rq + i][dc * 4];
        kv[i] = *(const floatx4*)&kvs[rc + i][dc * 4];
      }
      #pragma unroll
      for (int i = 0; i < 4; i++)
        #pragma unroll
        for (int j = 0; j < 4; j++)
          #pragma unroll
          for (int e = 0; e < 4; e++)
            sc[i][j] = fmaf(qv[i][e], kv[j][e], sc[i][j]);
    }
    #pragma unroll
    for (int i = 0; i < 4; i++){
      floatx4 sv;
      #pragma unroll
      for (int j = 0; j < 4; j++) sv[j] = sc[i][j] * scale;
      *(floatx4*)&ps[rq + i][rc] = sv;
    }
    __syncthreads();
    // ---- load V (reuses kvs) while lane-rows do the max reduction
    { const float* vh = vg + ((size_t)hd * 1024 + kb * 64) * 80;
      for (int c = tid; c < 64 * 20; c += 256){
        int r = c / 20, d4 = (c - r * 20) * 4;
        *(floatx4*)&kvs[r][d4] = *(const floatx4*)(vh + r * 80 + d4);
      } }
    if (tid < 64){
      float mx = -3e38f;
      for (int k2 = 0; k2 < 64; k2++) mx = fmaxf(mx, ps[tid][k2]);
      float mn = fmaxf(mrow[tid], mx);
      crow[tid] = __expf(mrow[tid] - mn);
      mrow[tid] = mn;
    }
    __syncthreads();
    // ---- exponentiate (contiguous assignment) + partial row sums
    { const int er = tid >> 2, ec = (tid & 3) * 16;
      float mr = mrow[er];
      float lsum = 0.f;
      #pragma unroll
      for (int c4 = 0; c4 < 4; c4++){
        floatx4 v = *(const floatx4*)&ps[er][ec + c4 * 4];
        #pragma unroll
        for (int e = 0; e < 4; e++){ float p = __expf(v[e] - mr); v[e] = p; lsum += p; }
        *(floatx4*)&ps[er][ec + c4 * 4] = v;
      }
      psum[er][tid & 3] = lsum;
    }
    __syncthreads();
    if (tid < 64)
      lrow[tid] = lrow[tid] * crow[tid] + psum[tid][0] + psum[tid][1] + psum[tid][2] + psum[tid][3];
    // ---- PV accumulate (rescale then add)
    { float cr = crow[oqi];
      #pragma unroll
      for (int j = 0; j < 20; j++) oacc[j] *= cr;
      for (int k2 = 0; k2 < 64; k2++){
        float p = ps[oqi][k2];
        const float* vr = &kvs[k2][od];
        #pragma unroll
        for (int c4 = 0; c4 < 5; c4++){
          floatx4 vvv = *(const floatx4*)(vr + c4 * 4);
          oacc[c4 * 4 + 0] = fmaf(p, vvv[0], oacc[c4 * 4 + 0]);
          oacc[c4 * 4 + 1] = fmaf(p, vvv[1], oacc[c4 * 4 + 1]);
          oacc[c4 * 4 + 2] = fmaf(p, vvv[2], oacc[c4 * 4 + 2]);
          oacc[c4 * 4 + 3] = fmaf(p, vvv[3], oacc[c4 * 4 + 3]);
        }
      }
    }
  }
  __syncthreads();
  float linv = 1.f / lrow[oqi];
  float* orow = og + (size_t)(qb * 64 + oqi) * 1280 + hd * 80 + od;
  #pragma unroll
  for (int c4 = 0; c4 < 5; c4++){
    floatx4 vvv;
    vvv[0] = oacc[c4 * 4 + 0] * linv;
    vvv[1] = oacc[c4 * 4 + 1] * linv;
    vvv[2] = oacc[c4 * 4 + 2] * linv;
    vvv[3] = oacc[c4 * 4 + 3] * linv;
    *(floatx4*)(orow + c4 * 4) = vvv;
  }
}

// =======================================================================
extern "C" void kernel_launch(void* const* d_in, const int* in_sizes, int n_in,
                              void* d_out, int out_size, void* d_ws, size_t ws_size,
                              hipStream_t stream)
{
  (void)in_sizes; (void)n_in; (void)out_size;
  const float* images  = (const float*)d_in[0];
  const int*   win     = (const int*)  d_in[1];
  const float* rpe     = (const float*)d_in[3];
  const float* patch_w = (const float*)d_in[6];
  const float* ln1_w   = (const float*)d_in[7];
  const float* ln2_w   = (const float*)d_in[8];
  const float* qkv_w   = (const float*)d_in[9];
  const float* qkv_b   = (const float*)d_in[10];
  const float* proj_w  = (const float*)d_in[11];
  const float* proj_b  = (const float*)d_in[12];
  const float* gate_w  = (const float*)d_in[13];
  const float* gate_b  = (const float*)d_in[14];
  const float* up_w    = (const float*)d_in[15];
  const float* up_b    = (const float*)d_in[16];
  const float* down_w  = (const float*)d_in[17];
  const float* down_b  = (const float*)d_in[18];
  const float* lnq_w   = (const float*)d_in[19];
  const float* m1_w    = (const float*)d_in[20];
  const float* m1_b    = (const float*)d_in[21];
  const float* m2_w    = (const float*)d_in[22];
  const float* m2_b    = (const float*)d_in[23];

  char* ws = (char*)d_ws;
  size_t off = 0;
  auto alloc = [&](size_t b){ size_t o = off; off += (b + 255) & ~(size_t)255; return o; };
  float* X    = (float*)(ws + alloc(1024ull * 1184 * 4));
  float* PW   = (float*)(ws + alloc(1184ull * 1280 * 4));
  float* H    = (float*)(ws + alloc(1024ull * 1280 * 4));
  float* AN   = (float*)(ws + alloc(1024ull * 1280 * 4));
  float* QKV  = (float*)(ws + alloc(1024ull * 3840 * 4));
  float* QH   = (float*)(ws + alloc(16ull * 1024 * 80 * 4));
  float* KH   = (float*)(ws + alloc(16ull * 1024 * 80 * 4));
  float* VH   = (float*)(ws + alloc(16ull * 1024 * 80 * 4));
  float* O    = (float*)(ws + alloc(1024ull * 1280 * 4));
  float* Ubuf = (float*)(ws + alloc(1024ull * 3456 * 4));
  float* DACT = (float*)(ws + alloc(1024ull * 3456 * 4));
  float* COSb = (float*)(ws + alloc(1024ull * 80 * 4));
  float* SINb = (float*)(ws + alloc(1024ull * 80 * 4));
  float* G    = QKV;   // alias: qkv dead before gate written
  float* G1   = QH;    // alias: q dead before merger (256*5120*4 == 16*1024*80*4)
  if (off > ws_size) return;  // ws too small -> leave output zero (clean fail)

  pad_pw_kernel     <<<5920, 256, 0, stream>>>(patch_w, PW);
  gather_x_kernel   <<<4736, 256, 0, stream>>>(images, win, X);
  rope_tables_kernel<<<320,  256, 0, stream>>>(rpe, win, COSb, SINb);

  // patch embed: X(1024x1184) @ PW(1184x1280) -> H
  gemm_kernel<64, 64, 0><<<dim3(20, 16), 256, 0, stream>>>(
      X, PW, nullptr, nullptr, H, nullptr, 1024, 1280, 1184);

  for (int i = 0; i < 8; i++){
    rmsnorm_kernel<<<1024, 256, 0, stream>>>(H, ln1_w + (size_t)i * 1280, AN, 1280);
    gemm_kernel<128, 128, 0><<<dim3(30, 8), 256, 0, stream>>>(
        AN, qkv_w + (size_t)i * 1280 * 3840, qkv_b + (size_t)i * 3840,
        nullptr, QKV, nullptr, 1024, 3840, 1280);
    rope_apply_kernel<<<5120, 256, 0, stream>>>(QKV, COSb, SINb, QH, KH, VH);
    if (i == 3 || i == 7)
      attn_kernel<true ><<<dim3(16, 16), 256, 0, stream>>>(QH, KH, VH, O);
    else
      attn_kernel<false><<<dim3(16, 16), 256, 0, stream>>>(QH, KH, VH, O);
    gemm_kernel<64, 64, 1><<<dim3(20, 16), 256, 0, stream>>>(
        O, proj_w + (size_t)i * 1280 * 1280, proj_b + (size_t)i * 1280,
        H, H, nullptr, 1024, 1280, 1280);
    rmsnorm_kernel<<<1024, 256, 0, stream>>>(H, ln2_w + (size_t)i * 1280, AN, 1280);
    gemm_kernel<64, 128, 0><<<dim3(27, 16), 256, 0, stream>>>(
        AN, gate_w + (size_t)i * 1280 * 3456, gate_b + (size_t)i * 3456,
        nullptr, G, nullptr, 1024, 3456, 1280);
    gemm_kernel<64, 128, 0><<<dim3(27, 16), 256, 0, stream>>>(
        AN, up_w + (size_t)i * 1280 * 3456, up_b + (size_t)i * 3456,
        nullptr, Ubuf, nullptr, 1024, 3456, 1280);
    silu_mul_kernel<<<13824, 256, 0, stream>>>(G, Ubuf, DACT, 1024 * 3456);
    gemm_kernel<64, 64, 1><<<dim3(20, 16), 256, 0, stream>>>(
        DACT, down_w + (size_t)i * 3456 * 1280, down_b + (size_t)i * 1280,
        H, H, nullptr, 1024, 1280, 3456);
  }

  // merger: rmsnorm -> (256,5120) @ m1 (gelu) -> @ m2 (scatter rows by win)
  rmsnorm_kernel<<<1024, 256, 0, stream>>>(H, lnq_w, AN, 1280);
  gemm_kernel<64, 64, 2><<<dim3(80, 4), 256, 0, stream>>>(
      AN, m1_w, m1_b, nullptr, G1, nullptr, 256, 5120, 5120);
  gemm_kernel<64, 64, 3><<<dim3(56, 4), 256, 0, stream>>>(
      G1, m2_w, m2_b, nullptr, (float*)d_out, win, 256, 3584, 5120);
}

// Round 2
// 3391.639 us; speedup vs baseline: 2.4324x; 2.4324x over previous
//
#include <hip/hip_runtime.h>
#include <math.h>

typedef float  floatx4  __attribute__((ext_vector_type(4)));
typedef int    intx4    __attribute__((ext_vector_type(4)));
typedef unsigned short ushortx8 __attribute__((ext_vector_type(8)));

// ---------- bf16 helpers (RNE) ----------
__device__ inline unsigned short f2bf(float x){
  unsigned u = __float_as_uint(x);
  u += 0x7FFFu + ((u >> 16) & 1u);
  return (unsigned short)(u >> 16);
}
__device__ inline float bf2f(unsigned short b){ return __uint_as_float(((unsigned)b) << 16); }
__device__ inline void split_bf(float x, unsigned short& h, unsigned short& l){
  h = f2bf(x); l = f2bf(x - bf2f(h));
}

// ---------- MFMA 16x16x32 bf16 ----------
// A-frag: lane l holds A[l&15][(l>>4)*8+j]; B-frag: lane l holds B[(l>>4)*8+j][l&15]
// C/D: lane l reg r = D[(l>>4)*4+r][l&15]   (verified passing in round 1)
__device__ inline void mfma_bf16(floatx4& acc, intx4 a, intx4 b){
  asm("v_mfma_f32_16x16x32_bf16 %0, %1, %2, %0" : "+v"(acc) : "v"(a), "v"(b));
}

// ---------- async global->LDS, 16B per lane ----------
__device__ inline void gld_lds16(const void* g, void* l){
  __builtin_amdgcn_global_load_lds(
      (const __attribute__((address_space(1))) unsigned int*)g,
      (__attribute__((address_space(3))) unsigned int*)l, 16, 0, 0);
}

// =======================================================================
// Dual-plane bf16 GEMM: out[M,N] = (Ah+Al)[M,K] @ (Wh+Wl)^T[N,K]
// A planes: [M][K] bf16 (hi, lo). W planes: [N][K] bf16 (pre-transposed).
// Double-buffered LDS, global_load_lds staging with XOR-swizzled source,
// 3 MFMAs per fragment pair (al*wh + ah*wl + ah*wh).
// MODE 0: outf = acc + bias
// MODE 1: outf = acc + bias + res (residual, res may alias outf)
// MODE 2: planes out = gelu_exact(acc + bias) -> outh/outl
// MODE 3: outf[rowmap[row]*Nout + col] = acc + bias (row scatter)
// =======================================================================
template<int BM, int BN, int MODE>
__global__ __launch_bounds__(256) void gemm_bf2(
    const unsigned short* __restrict__ Ah, const unsigned short* __restrict__ Al,
    const unsigned short* __restrict__ Wh, const unsigned short* __restrict__ Wl,
    const float* __restrict__ bias, const float* __restrict__ res,
    float* __restrict__ outf, unsigned short* __restrict__ outh,
    unsigned short* __restrict__ outl, const int* __restrict__ rowmap,
    int K, int Nout, int out_col0)
{
  __shared__ unsigned short SA[2][2][BM*32];
  __shared__ unsigned short SW[2][2][BN*32];
  const int tid = threadIdx.x, lane = tid & 63, wv = tid >> 6;
  const int wm = wv >> 1, wn = wv & 1;
  const int m0 = blockIdx.y * BM, n0 = blockIdx.x * BN;
  constexpr int MR = BM / 32, NR = BN / 32;
  floatx4 acc[MR][NR];
  #pragma unroll
  for (int mr = 0; mr < MR; mr++)
    #pragma unroll
    for (int nr = 0; nr < NR; nr++) acc[mr][nr] = 0.f;
  const int fr = lane & 15, kg = lane >> 4;

  auto stage = [&](int buf, int k0){
    #pragma unroll
    for (int sh = 0; sh < (BM * 4) / 256; sh++){
      int s = sh * 256 + tid;
      int row = s >> 2, ck = (s & 3) ^ ((row >> 1) & 3);
      size_t go = (size_t)(m0 + row) * K + k0 + ck * 8;
      gld_lds16(Ah + go, &SA[buf][0][(sh * 256 + wv * 64) * 8]);
      gld_lds16(Al + go, &SA[buf][1][(sh * 256 + wv * 64) * 8]);
    }
    #pragma unroll
    for (int sh = 0; sh < (BN * 4) / 256; sh++){
      int s = sh * 256 + tid;
      int row = s >> 2, ck = (s & 3) ^ ((row >> 1) & 3);
      size_t go = (size_t)(n0 + row) * K + k0 + ck * 8;
      gld_lds16(Wh + go, &SW[buf][0][(sh * 256 + wv * 64) * 8]);
      gld_lds16(Wl + go, &SW[buf][1][(sh * 256 + wv * 64) * 8]);
    }
  };

  stage(0, 0);
  __syncthreads();
  const int nt = K >> 5;
  for (int t = 0; t < nt; t++){
    const int buf = t & 1;
    if (t + 1 < nt) stage(buf ^ 1, (t + 1) << 5);   // prefetch next tile
    intx4 ah[MR], al[MR], wh[NR], wl[NR];
    #pragma unroll
    for (int mr = 0; mr < MR; mr++){
      int r = wm * (BM / 2) + mr * 16 + fr;
      int off = r * 64 + ((kg ^ ((r >> 1) & 3)) << 4);
      ah[mr] = *(const intx4*)((const char*)&SA[buf][0][0] + off);
      al[mr] = *(const intx4*)((const char*)&SA[buf][1][0] + off);
    }
    #pragma unroll
    for (int nr = 0; nr < NR; nr++){
      int r = wn * (BN / 2) + nr * 16 + fr;
      int off = r * 64 + ((kg ^ ((r >> 1) & 3)) << 4);
      wh[nr] = *(const intx4*)((const char*)&SW[buf][0][0] + off);
      wl[nr] = *(const intx4*)((const char*)&SW[buf][1][0] + off);
    }
    #pragma unroll
    for (int mr = 0; mr < MR; mr++)
      #pragma unroll
      for (int nr = 0; nr < NR; nr++){
        mfma_bf16(acc[mr][nr], al[mr], wh[nr]);
        mfma_bf16(acc[mr][nr], ah[mr], wl[nr]);
        mfma_bf16(acc[mr][nr], ah[mr], wh[nr]);
      }
    __syncthreads();   // drains prefetch (vmcnt 0) + protects buf reuse
  }
  asm volatile("s_nop 7\n\ts_nop 7" ::: "memory");
  #pragma unroll
  for (int mr = 0; mr < MR; mr++)
    #pragma unroll
    for (int nr = 0; nr < NR; nr++){
      int np  = n0 + wn * (BN / 2) + nr * 16 + fr;
      int col = out_col0 + np;
      float bv = bias ? bias[np] : 0.f;
      #pragma unroll
      for (int e = 0; e < 4; e++){
        int row = m0 + wm * (BM / 2) + mr * 16 + kg * 4 + e;
        float v = acc[mr][nr][e] + bv;
        if (MODE == 1) v += res[(size_t)row * Nout + col];
        if (MODE == 2){
          v = 0.5f * v * (1.f + erff(v * 0.70710678118654752f));
          unsigned short h, l; split_bf(v, h, l);
          outh[(size_t)row * Nout + col] = h;
          outl[(size_t)row * Nout + col] = l;
        } else if (MODE == 3){
          outf[(size_t)rowmap[row] * Nout + col] = v;
        } else {
          outf[(size_t)row * Nout + col] = v;
        }
      }
    }
}

// =======================================================================
// Weight conversion: W f32 [K][Nstride] (col slice at n_src0) ->
// transposed hi/lo bf16 planes [N][Kpad], zero-padded for k >= K.
// grid: (Kpad/64, Ncols/64), block 256.
// =======================================================================
__global__ __launch_bounds__(256) void convert_w_kernel(
    const float* __restrict__ W, unsigned short* __restrict__ PH,
    unsigned short* __restrict__ PL,
    int K, int Nstride, int n_src0, int Kpad, int plane_row0)
{
  __shared__ float T[64][68];
  const int tid = threadIdx.x;
  const int k0 = blockIdx.x * 64, n0 = blockIdx.y * 64;
  const int kr = tid >> 4, nc = (tid & 15) << 2;
  #pragma unroll
  for (int p = 0; p < 4; p++){
    int k = k0 + p * 16 + kr;
    floatx4 v = {0.f, 0.f, 0.f, 0.f};
    if (k < K) v = *(const floatx4*)(W + (size_t)k * Nstride + n_src0 + n0 + nc);
    *(floatx4*)&T[p * 16 + kr][nc] = v;
  }
  __syncthreads();
  const int n = tid >> 2, kc = (tid & 3) << 4;
  ushortx8 h0, h1, l0, l1;
  #pragma unroll
  for (int j = 0; j < 8; j++){
    unsigned short h, l;
    split_bf(T[kc + j][n], h, l);       h0[j] = h; l0[j] = l;
    split_bf(T[kc + 8 + j][n], h, l);   h1[j] = h; l1[j] = l;
  }
  size_t ro = (size_t)(plane_row0 + n0 + n) * Kpad + k0 + kc;
  *(ushortx8*)&PH[ro] = h0; *(ushortx8*)&PH[ro + 8] = h1;
  *(ushortx8*)&PL[ro] = l0; *(ushortx8*)&PL[ro + 8] = l1;
}

// =======================================================================
// RMSNorm: f32 row in -> hi/lo bf16 plane out. One block per row, D=1280.
// =======================================================================
__global__ __launch_bounds__(256) void rmsnorm_kernel(
    const float* __restrict__ x, const float* __restrict__ w,
    unsigned short* __restrict__ yh, unsigned short* __restrict__ yl)
{
  const int row = blockIdx.x;
  const float* xr = x + (size_t)row * 1280;
  float ss = 0.f;
  for (int i = threadIdx.x; i < 1280; i += 256){ float v = xr[i]; ss = fmaf(v, v, ss); }
  for (int o = 32; o > 0; o >>= 1) ss += __shfl_down(ss, o);
  __shared__ float wsum[4];
  __shared__ float snorm;
  if ((threadIdx.x & 63) == 0) wsum[threadIdx.x >> 6] = ss;
  __syncthreads();
  if (threadIdx.x == 0){
    float t = wsum[0] + wsum[1] + wsum[2] + wsum[3];
    snorm = 1.0f / sqrtf(t * (1.0f / 1280.0f) + 1e-6f);
  }
  __syncthreads();
  float s = snorm;
  for (int i = threadIdx.x; i < 1280; i += 256){
    float v = xr[i] * s * w[i];
    unsigned short h, l; split_bf(v, h, l);
    yh[(size_t)row * 1280 + i] = h;
    yl[(size_t)row * 1280 + i] = l;
  }
}

// =======================================================================
// Patch gather (window perm folded) -> hi/lo planes [1024][1216]
// =======================================================================
__global__ __launch_bounds__(256) void gather_x_kernel(
    const float* __restrict__ img, const int* __restrict__ win,
    unsigned short* __restrict__ Xh, unsigned short* __restrict__ Xl)
{
  int idx = blockIdx.x * 256 + threadIdx.x;
  if (idx >= 1024 * 1216) return;
  int s = idx / 1216, f = idx - s * 1216;
  float val = 0.f;
  if (f < 1176){
    int sp = (win[s >> 2] << 2) | (s & 3);
    int i0 = sp >> 6, r = sp & 63;
    int i3 = r >> 2, rr = r & 3, i1 = rr >> 1, i4 = rr & 1;
    int c  = f / 392, f2 = f - c * 392;
    int f3 = f2 % 196;
    int ph = f3 / 14, pw2 = f3 - ph * 14;
    int hp = (i0 * 2 + i1) * 14 + ph, wp = (i3 * 2 + i4) * 14 + pw2;
    val = img[((size_t)c * 448 + hp) * 448 + wp];
  }
  unsigned short h, l; split_bf(val, h, l);
  Xh[idx] = h; Xl[idx] = l;
}

// cos/sin tables (1024 x 80), window permutation folded in
__global__ __launch_bounds__(256) void rope_tables_kernel(
    const float* __restrict__ rpe, const int* __restrict__ win,
    float* __restrict__ cosb, float* __restrict__ sinb)
{
  int idx = blockIdx.x * 256 + threadIdx.x;
  if (idx >= 1024 * 80) return;
  int s = idx / 80, d = idx - s * 80;
  int src = (win[s >> 2] << 2) | (s & 3);
  float ang = rpe[src * 40 + (d % 40)];
  cosb[idx] = cosf(ang);
  sinb[idx] = sinf(ang);
}

// qkv (S,3,16,80) f32 -> rope(q,k), head-major q/k/v (16,1024,80) f32
__global__ __launch_bounds__(256) void rope_apply_kernel(
    const float* __restrict__ qkv, const float* __restrict__ cosb, const float* __restrict__ sinb,
    float* __restrict__ qh, float* __restrict__ kh, float* __restrict__ vh)
{
  int idx = blockIdx.x * 256 + threadIdx.x;
  if (idx >= 1024 * 16 * 80) return;
  int s = idx / 1280, rem = idx - s * 1280;
  int hd = rem / 80, d = rem - hd * 80;
  const float* base = qkv + (size_t)s * 3840;
  float qv = base[hd * 80 + d];
  float kv = base[1280 + hd * 80 + d];
  float vv = base[2560 + hd * 80 + d];
  float qo = (d < 40) ? -base[hd * 80 + d + 40] : base[hd * 80 + d - 40];
  float ko = (d < 40) ? -base[1280 + hd * 80 + d + 40] : base[1280 + hd * 80 + d - 40];
  float cc = cosb[s * 80 + d], sn = sinb[s * 80 + d];
  size_t o = ((size_t)hd * 1024 + s) * 80 + d;
  qh[o] = qv * cc + qo * sn;
  kh[o] = kv * cc + ko * sn;
  vh[o] = vv;
}

// silu(g)*u from fused GU buffer -> hi/lo planes. grid (27, 1024), block 128.
__global__ __launch_bounds__(128) void silu_mul_kernel(
    const float* __restrict__ gu,
    unsigned short* __restrict__ dh, unsigned short* __restrict__ dl)
{
  int col = blockIdx.x * 128 + threadIdx.x;
  int row = blockIdx.y;
  float g = gu[(size_t)row * 6912 + col];
  float u = gu[(size_t)row * 6912 + 3456 + col];
  float sv = g / (1.f + __expf(-g)) * u;
  unsigned short h, l; split_bf(sv, h, l);
  dh[(size_t)row * 3456 + col] = h;
  dl[(size_t)row * 3456 + col] = l;
}

// concat gate_b/up_b for all 8 layers -> [8][6912]
__global__ __launch_bounds__(256) void concat_bias_kernel(
    const float* __restrict__ gb, const float* __restrict__ ub, float* __restrict__ out)
{
  int idx = blockIdx.x * 256 + threadIdx.x;
  if (idx >= 8 * 6912) return;
  int l = idx / 6912, j = idx - l * 6912;
  out[idx] = (j < 3456) ? gb[l * 3456 + j] : ub[l * 3456 + j - 3456];
}

// =======================================================================
// Attention (f32, flash-style), emits hi/lo planes for proj's A operand.
// =======================================================================
template<bool FULL>
__global__ __launch_bounds__(256) void attn_kernel(
    const float* __restrict__ qg, const float* __restrict__ kg,
    const float* __restrict__ vg,
    unsigned short* __restrict__ Oh, unsigned short* __restrict__ Ol)
{
  __shared__ float qs[64][84];
  __shared__ float kvs[64][84];
  __shared__ float ps[64][68];
  __shared__ float mrow[64], lrow[64], crow[64], psum[64][4];
  const int tid = threadIdx.x;
  const int qb = blockIdx.x, hd = blockIdx.y;
  const float scale = 0.11180339887498949f;

  const float* qh = qg + ((size_t)hd * 1024 + qb * 64) * 80;
  for (int c = tid; c < 64 * 20; c += 256){
    int r = c / 20, d4 = (c - r * 20) * 4;
    *(floatx4*)&qs[r][d4] = *(const floatx4*)(qh + r * 80 + d4);
  }
  if (tid < 64){ mrow[tid] = -3e38f; lrow[tid] = 0.f; }
  float oacc[20];
  #pragma unroll
  for (int j = 0; j < 20; j++) oacc[j] = 0.f;

  const int rq = (tid >> 4) * 4, rc = (tid & 15) * 4;
  const int oqi = tid >> 2, od = (tid & 3) * 20;
  const int kb0 = FULL ? 0 : qb, kb1 = FULL ? 16 : qb + 1;

  for (int kb = kb0; kb < kb1; kb++){
    __syncthreads();
    { const float* kh = kg + ((size_t)hd * 1024 + kb * 64) * 80;
      for (int c = tid; c < 64 * 20; c += 256){
        int r = c / 20, d4 = (c - r * 20) * 4;
        *(floatx4*)&kvs[r][d4] = *(const floatx4*)(kh + r * 80 + d4);
      } }
    __syncthreads();
    float sc[4][4];
    #pragma unroll
    for (int i = 0; i < 4; i++)
      #pragma unroll
      for (int j = 0; j < 4; j++) sc[i][j] = 0.f;
    for (int dc = 0; dc < 20; dc++){
      floatx4 qv[4], kv[4];
      #pragma unroll
      for (int i = 0; i < 4; i++){
        qv[i] = *(const floatx4*)&qs[rq + i][dc * 4];
        kv[i] = *(const floatx4*)&kvs[rc + i][dc * 4];
      }
      #pragma unroll
      for (int i = 0; i < 4; i++)
        #pragma unroll
        for (int j = 0; j < 4; j++)
          #pragma unroll
          for (int e = 0; e < 4; e++)
            sc[i][j] = fmaf(qv[i][e], kv[j][e], sc[i][j]);
    }
    #pragma unroll
    for (int i = 0; i < 4; i++){
      floatx4 sv;
      #pragma unroll
      for (int j = 0; j < 4; j++) sv[j] = sc[i][j] * scale;
      *(floatx4*)&ps[rq + i][rc] = sv;
    }
    __syncthreads();
    { const float* vh = vg + ((size_t)hd * 1024 + kb * 64) * 80;
      for (int c = tid; c < 64 * 20; c += 256){
        int r = c / 20, d4 = (c - r * 20) * 4;
        *(floatx4*)&kvs[r][d4] = *(const floatx4*)(vh + r * 80 + d4);
      } }
    if (tid < 64){
      float mx = -3e38f;
      for (int k2 = 0; k2 < 64; k2++) mx = fmaxf(mx, ps[tid][k2]);
      float mn = fmaxf(mrow[tid], mx);
      crow[tid] = __expf(mrow[tid] - mn);
      mrow[tid] = mn;
    }
    __syncthreads();
    { const int er = tid >> 2, ec = (tid & 3) * 16;
      float mr = mrow[er];
      float lsum = 0.f;
      #pragma unroll
      for (int c4 = 0; c4 < 4; c4++){
        floatx4 v = *(const floatx4*)&ps[er][ec + c4 * 4];
        #pragma unroll
        for (int e = 0; e < 4; e++){ float p = __expf(v[e] - mr); v[e] = p; lsum += p; }
        *(floatx4*)&ps[er][ec + c4 * 4] = v;
      }
      psum[er][tid & 3] = lsum;
    }
    __syncthreads();
    if (tid < 64)
      lrow[tid] = lrow[tid] * crow[tid] + psum[tid][0] + psum[tid][1] + psum[tid][2] + psum[tid][3];
    { float cr = crow[oqi];
      #pragma unroll
      for (int j = 0; j < 20; j++) oacc[j] *= cr;
      for (int k2 = 0; k2 < 64; k2++){
        float p = ps[oqi][k2];
        const float* vr = &kvs[k2][od];
        #pragma unroll
        for (int c4 = 0; c4 < 5; c4++){
          floatx4 vvv = *(const floatx4*)(vr + c4 * 4);
          oacc[c4 * 4 + 0] = fmaf(p, vvv[0], oacc[c4 * 4 + 0]);
          oacc[c4 * 4 + 1] = fmaf(p, vvv[1], oacc[c4 * 4 + 1]);
          oacc[c4 * 4 + 2] = fmaf(p, vvv[2], oacc[c4 * 4 + 2]);
          oacc[c4 * 4 + 3] = fmaf(p, vvv[3], oacc[c4 * 4 + 3]);
        }
      }
    }
  }
  __syncthreads();
  float linv = 1.f / lrow[oqi];
  size_t base = (size_t)(qb * 64 + oqi) * 1280 + hd * 80 + od;
  #pragma unroll
  for (int j = 0; j < 20; j++){
    float v = oacc[j] * linv;
    unsigned short h, l; split_bf(v, h, l);
    Oh[base + j] = h; Ol[base + j] = l;
  }
}

// =======================================================================
extern "C" void kernel_launch(void* const* d_in, const int* in_sizes, int n_in,
                              void* d_out, int out_size, void* d_ws, size_t ws_size,
                              hipStream_t stream)
{
  (void)in_sizes; (void)n_in; (void)out_size;
  const float* images  = (const float*)d_in[0];
  const int*   win     = (const int*)  d_in[1];
  const float* rpe     = (const float*)d_in[3];
  const float* patch_w = (const float*)d_in[6];
  const float* ln1_w   = (const float*)d_in[7];
  const float* ln2_w   = (const float*)d_in[8];
  const float* qkv_w   = (const float*)d_in[9];
  const float* qkv_b   = (const float*)d_in[10];
  const float* proj_w  = (const float*)d_in[11];
  const float* proj_b  = (const float*)d_in[12];
  const float* gate_w  = (const float*)d_in[13];
  const float* gate_b  = (const float*)d_in[14];
  const float* up_w    = (const float*)d_in[15];
  const float* up_b    = (const float*)d_in[16];
  const float* down_w  = (const float*)d_in[17];
  const float* down_b  = (const float*)d_in[18];
  const float* lnq_w   = (const float*)d_in[19];
  const float* m1_w    = (const float*)d_in[20];
  const float* m1_b    = (const float*)d_in[21];
  const float* m2_w    = (const float*)d_in[22];
  const float* m2_b    = (const float*)d_in[23];

  char* ws = (char*)d_ws;
  size_t off = 0;
  auto alloc = [&](size_t b){ size_t o = off; off += (b + 255) & ~(size_t)255; return o; };
  unsigned short* WPH  = (unsigned short*)(ws + alloc(13107200ull * 2));
  unsigned short* WPL  = (unsigned short*)(ws + alloc(13107200ull * 2));
  unsigned short* Xh   = (unsigned short*)(ws + alloc(1024ull * 1216 * 2));
  unsigned short* Xl   = (unsigned short*)(ws + alloc(1024ull * 1216 * 2));
  unsigned short* ANh  = (unsigned short*)(ws + alloc(1024ull * 1280 * 2));
  unsigned short* ANl  = (unsigned short*)(ws + alloc(1024ull * 1280 * 2));
  float* H    = (float*)(ws + alloc(1024ull * 1280 * 4));
  float* QKV  = (float*)(ws + alloc(1024ull * 3840 * 4));
  float* QH   = (float*)(ws + alloc(16ull * 1024 * 80 * 4));
  float* KH   = (float*)(ws + alloc(16ull * 1024 * 80 * 4));
  float* VH   = (float*)(ws + alloc(16ull * 1024 * 80 * 4));
  unsigned short* Ohh = (unsigned short*)(ws + alloc(1024ull * 1280 * 2));
  unsigned short* Oll = (unsigned short*)(ws + alloc(1024ull * 1280 * 2));
  float* GU   = (float*)(ws + alloc(1024ull * 6912 * 4));
  unsigned short* DAh = (unsigned short*)(ws + alloc(1024ull * 3456 * 2));
  unsigned short* DAl = (unsigned short*)(ws + alloc(1024ull * 3456 * 2));
  unsigned short* G1h = (unsigned short*)(ws + alloc(256ull * 5120 * 2));
  unsigned short* G1l = (unsigned short*)(ws + alloc(256ull * 5120 * 2));
  float* COSb = (float*)(ws + alloc(1024ull * 80 * 4));
  float* SINb = (float*)(ws + alloc(1024ull * 80 * 4));
  float* BGU  = (float*)(ws + alloc(8ull * 6912 * 4));
  if (off > ws_size) return;

  gather_x_kernel   <<<4864, 256, 0, stream>>>(images, win, Xh, Xl);
  rope_tables_kernel<<<320,  256, 0, stream>>>(rpe, win, COSb, SINb);
  concat_bias_kernel<<<216,  256, 0, stream>>>(gate_b, up_b, BGU);

  // patch embed
  convert_w_kernel<<<dim3(19, 20), 256, 0, stream>>>(patch_w, WPH, WPL, 1176, 1280, 0, 1216, 0);
  gemm_bf2<64, 64, 0><<<dim3(20, 16), 256, 0, stream>>>(
      Xh, Xl, WPH, WPL, nullptr, nullptr, H, nullptr, nullptr, nullptr, 1216, 1280, 0);

  for (int i = 0; i < 8; i++){
    rmsnorm_kernel<<<1024, 256, 0, stream>>>(H, ln1_w + (size_t)i * 1280, ANh, ANl);
    convert_w_kernel<<<dim3(20, 60), 256, 0, stream>>>(
        qkv_w + (size_t)i * 1280 * 3840, WPH, WPL, 1280, 3840, 0, 1280, 0);
    gemm_bf2<64, 128, 0><<<dim3(30, 16), 256, 0, stream>>>(
        ANh, ANl, WPH, WPL, qkv_b + (size_t)i * 3840, nullptr,
        QKV, nullptr, nullptr, nullptr, 1280, 3840, 0);
    rope_apply_kernel<<<5120, 256, 0, stream>>>(QKV, COSb, SINb, QH, KH, VH);
    if (i == 3 || i == 7)
      attn_kernel<true ><<<dim3(16, 16), 256, 0, stream>>>(QH, KH, VH, Ohh, Oll);
    else
      attn_kernel<false><<<dim3(16, 16), 256, 0, stream>>>(QH, KH, VH, Ohh, Oll);
    convert_w_kernel<<<dim3(20, 20), 256, 0, stream>>>(
        proj_w + (size_t)i * 1280 * 1280, WPH, WPL, 1280, 1280, 0, 1280, 0);
    gemm_bf2<64, 64, 1><<<dim3(20, 16), 256, 0, stream>>>(
        Ohh, Oll, WPH, WPL, proj_b + (size_t)i * 1280, H,
        H, nullptr, nullptr, nullptr, 1280, 1280, 0);
    rmsnorm_kernel<<<1024, 256, 0, stream>>>(H, ln2_w + (size_t)i * 1280, ANh, ANl);
    convert_w_kernel<<<dim3(20, 54), 256, 0, stream>>>(
        gate_w + (size_t)i * 1280 * 3456, WPH, WPL, 1280, 3456, 0, 1280, 0);
    convert_w_kernel<<<dim3(20, 54), 256, 0, stream>>>(
        up_w + (size_t)i * 1280 * 3456, WPH, WPL, 1280, 3456, 0, 1280, 3456);
    gemm_bf2<64, 128, 0><<<dim3(54, 16), 256, 0, stream>>>(
        ANh, ANl, WPH, WPL, BGU + (size_t)i * 6912, nullptr,
        GU, nullptr, nullptr, nullptr, 1280, 6912, 0);
    silu_mul_kernel<<<dim3(27, 1024), 128, 0, stream>>>(GU, DAh, DAl);
    convert_w_kernel<<<dim3(54, 20), 256, 0, stream>>>(
        down_w + (size_t)i * 3456 * 1280, WPH, WPL, 3456, 1280, 0, 3456, 0);
    gemm_bf2<64, 64, 1><<<dim3(20, 16), 256, 0, stream>>>(
        DAh, DAl, WPH, WPL, down_b + (size_t)i * 1280, H,
        H, nullptr, nullptr, nullptr, 3456, 1280, 0);
  }

  // merger
  rmsnorm_kernel<<<1024, 256, 0, stream>>>(H, lnq_w, ANh, ANl);
  for (int h = 0; h < 2; h++){
    convert_w_kernel<<<dim3(80, 40), 256, 0, stream>>>(
        m1_w, WPH, WPL, 5120, 5120, h * 2560, 5120, 0);
    gemm_bf2<64, 64, 2><<<dim3(40, 4), 256, 0, stream>>>(
        ANh, ANl, WPH, WPL, m1_b + h * 2560, nullptr,
        nullptr, G1h, G1l, nullptr, 5120, 5120, h * 2560);
  }
  for (int h = 0; h < 2; h++){
    convert_w_kernel<<<dim3(80, 28), 256, 0, stream>>>(
        m2_w, WPH, WPL, 5120, 3584, h * 1792, 5120, 0);
    gemm_bf2<64, 64, 3><<<dim3(28, 4), 256, 0, stream>>>(
        G1h, G1l, WPH, WPL, m2_b + h * 1792, nullptr,
        (float*)d_out, nullptr, nullptr, win, 5120, 3584, h * 1792);
  }
}

// Round 3
// 3172.216 us; speedup vs baseline: 2.6007x; 1.0692x over previous
//
#include <hip/hip_runtime.h>
#include <math.h>

typedef float  floatx4  __attribute__((ext_vector_type(4)));
typedef short  short8   __attribute__((ext_vector_type(8)));
typedef unsigned short ushortx8 __attribute__((ext_vector_type(8)));

// ---------- bf16 helpers (RNE) ----------
__device__ inline unsigned short f2bf(float x){
  unsigned u = __float_as_uint(x);
  u += 0x7FFFu + ((u >> 16) & 1u);
  return (unsigned short)(u >> 16);
}
__device__ inline float bf2f(unsigned short b){ return __uint_as_float(((unsigned)b) << 16); }
__device__ inline void split_bf(float x, unsigned short& h, unsigned short& l){
  h = f2bf(x); l = f2bf(x - bf2f(h));
}

// ---------- MFMA 16x16x32 bf16 (builtin; compiler handles hazards) ----------
// A-frag: lane l holds A[l&15][(l>>4)*8+j]; B-frag: lane l holds B[(l>>4)*8+j][l&15]
// C/D: lane l reg r = D[(l>>4)*4+r][l&15]   (verified in rounds 1-2)
__device__ inline floatx4 mfma(short8 a, short8 b, floatx4 c){
  return __builtin_amdgcn_mfma_f32_16x16x32_bf16(a, b, c, 0, 0, 0);
}

// ---------- async global->LDS, 16B per lane ----------
__device__ inline void gld_lds16(const void* g, void* l){
  __builtin_amdgcn_global_load_lds(
      (const __attribute__((address_space(1))) unsigned int*)g,
      (__attribute__((address_space(3))) unsigned int*)l, 16, 0, 0);
}

// =======================================================================
// Dual-plane bf16 GEMM: out[M,N] = (Ah+Al)[M,K] @ (Wh+Wl)^T[N,K]
// Double-buffered LDS, global_load_lds staging, XOR-swizzled granules.
// MODE 0: outf = acc + bias
// MODE 1: outf = acc + bias + res (residual; res may alias outf)
// MODE 2: planes = gelu_exact(acc + bias)
// MODE 3: outf[rowmap[row]*Nout + col] = acc + bias (row scatter)
// MODE 4: interleaved gate/up -> planes = silu(g)*u at col>>1
// =======================================================================
template<int BM, int BN, int MODE>
__global__ __launch_bounds__(256) void gemm_bf2(
    const unsigned short* __restrict__ Ah, const unsigned short* __restrict__ Al,
    const unsigned short* __restrict__ Wh, const unsigned short* __restrict__ Wl,
    const float* __restrict__ bias, const float* __restrict__ res,
    float* __restrict__ outf, unsigned short* __restrict__ outh,
    unsigned short* __restrict__ outl, const int* __restrict__ rowmap,
    int K, int Nout, int out_col0)
{
  __shared__ unsigned short SA[2][2][BM*32];
  __shared__ unsigned short SW[2][2][BN*32];
  const int tid = threadIdx.x, lane = tid & 63, wv = tid >> 6;
  const int wm = wv >> 1, wn = wv & 1;
  const int m0 = blockIdx.y * BM, n0 = blockIdx.x * BN;
  constexpr int MR = BM / 32, NR = BN / 32;
  floatx4 acc[MR][NR];
  #pragma unroll
  for (int mr = 0; mr < MR; mr++)
    #pragma unroll
    for (int nr = 0; nr < NR; nr++) acc[mr][nr] = 0.f;
  const int fr = lane & 15, kg = lane >> 4;

  auto stage = [&](int buf, int k0){
    #pragma unroll
    for (int p = 0; p < (BM * 4) / 256; p++){
      int lin = p * 256 + tid;
      int row = lin >> 2, gg = (lin & 3) ^ ((row >> 1) & 3);
      size_t go = (size_t)(m0 + row) * K + k0 + gg * 8;
      gld_lds16(Ah + go, &SA[buf][0][(p * 256 + wv * 64) * 8]);
      gld_lds16(Al + go, &SA[buf][1][(p * 256 + wv * 64) * 8]);
    }
    #pragma unroll
    for (int p = 0; p < (BN * 4) / 256; p++){
      int lin = p * 256 + tid;
      int row = lin >> 2, gg = (lin & 3) ^ ((row >> 1) & 3);
      size_t go = (size_t)(n0 + row) * K + k0 + gg * 8;
      gld_lds16(Wh + go, &SW[buf][0][(p * 256 + wv * 64) * 8]);
      gld_lds16(Wl + go, &SW[buf][1][(p * 256 + wv * 64) * 8]);
    }
  };

  stage(0, 0);
  __syncthreads();
  const int nt = K >> 5;
  for (int t = 0; t < nt; t++){
    const int buf = t & 1;
    if (t + 1 < nt) stage(buf ^ 1, (t + 1) << 5);
    short8 ah[MR], al[MR], wh[NR], wl[NR];
    #pragma unroll
    for (int mr = 0; mr < MR; mr++){
      int r = wm * (BM / 2) + mr * 16 + fr;
      int off = r * 64 + ((kg ^ ((r >> 1) & 3)) << 4);
      ah[mr] = *(const short8*)((const char*)&SA[buf][0][0] + off);
      al[mr] = *(const short8*)((const char*)&SA[buf][1][0] + off);
    }
    #pragma unroll
    for (int nr = 0; nr < NR; nr++){
      int r = wn * (BN / 2) + nr * 16 + fr;
      int off = r * 64 + ((kg ^ ((r >> 1) & 3)) << 4);
      wh[nr] = *(const short8*)((const char*)&SW[buf][0][0] + off);
      wl[nr] = *(const short8*)((const char*)&SW[buf][1][0] + off);
    }
    #pragma unroll
    for (int mr = 0; mr < MR; mr++)
      #pragma unroll
      for (int nr = 0; nr < NR; nr++){
        acc[mr][nr] = mfma(al[mr], wh[nr], acc[mr][nr]);
        acc[mr][nr] = mfma(ah[mr], wl[nr], acc[mr][nr]);
        acc[mr][nr] = mfma(ah[mr], wh[nr], acc[mr][nr]);
      }
    __syncthreads();
  }
  #pragma unroll
  for (int mr = 0; mr < MR; mr++)
    #pragma unroll
    for (int nr = 0; nr < NR; nr++){
      int np  = n0 + wn * (BN / 2) + nr * 16 + fr;
      int col = out_col0 + np;
      float bv = bias ? bias[np] : 0.f;
      #pragma unroll
      for (int e = 0; e < 4; e++){
        int row = m0 + wm * (BM / 2) + mr * 16 + kg * 4 + e;
        float v = acc[mr][nr][e] + bv;
        if (MODE == 1) v += res[(size_t)row * Nout + col];
        if (MODE == 0 || MODE == 1) outf[(size_t)row * Nout + col] = v;
        if (MODE == 2){
          v = 0.5f * v * (1.f + erff(v * 0.70710678118654752f));
          unsigned short hh, ll; split_bf(v, hh, ll);
          outh[(size_t)row * Nout + col] = hh;
          outl[(size_t)row * Nout + col] = ll;
        }
        if (MODE == 3) outf[(size_t)rowmap[row] * Nout + col] = v;
        if (MODE == 4){
          float pv = __shfl_xor(v, 1);
          if (!(fr & 1)){
            float dv = v / (1.f + __expf(-v)) * pv;
            unsigned short hh, ll; split_bf(dv, hh, ll);
            outh[(size_t)row * Nout + (col >> 1)] = hh;
            outl[(size_t)row * Nout + (col >> 1)] = ll;
          }
        }
      }
    }
}

// =======================================================================
// Weight convert: W f32 [K][Nstride] (cols at n_src0) -> transposed hi/lo
// planes at row (plane_row0 + n*row_mul + row_add), [.][Kpad], zero-pad k>=K
// =======================================================================
__global__ __launch_bounds__(256) void convert_w_kernel(
    const float* __restrict__ W, unsigned short* __restrict__ PH,
    unsigned short* __restrict__ PL,
    int K, int Nstride, int n_src0, int Kpad, int plane_row0,
    int row_mul, int row_add)
{
  __shared__ float T[64][68];
  const int tid = threadIdx.x;
  const int k0 = blockIdx.x * 64, n0 = blockIdx.y * 64;
  const int kr = tid >> 4, nc = (tid & 15) << 2;
  #pragma unroll
  for (int p = 0; p < 4; p++){
    int k = k0 + p * 16 + kr;
    floatx4 v = {0.f, 0.f, 0.f, 0.f};
    if (k < K) v = *(const floatx4*)(W + (size_t)k * Nstride + n_src0 + n0 + nc);
    *(floatx4*)&T[p * 16 + kr][nc] = v;
  }
  __syncthreads();
  const int n = tid >> 2, kc = (tid & 3) << 4;
  ushortx8 h0, h1, l0, l1;
  #pragma unroll
  for (int j = 0; j < 8; j++){
    unsigned short h, l;
    split_bf(T[kc + j][n], h, l);       h0[j] = h; l0[j] = l;
    split_bf(T[kc + 8 + j][n], h, l);   h1[j] = h; l1[j] = l;
  }
  size_t ro = (size_t)(plane_row0 + (n0 + n) * row_mul + row_add) * Kpad + k0 + kc;
  *(ushortx8*)&PH[ro] = h0; *(ushortx8*)&PH[ro + 8] = h1;
  *(ushortx8*)&PL[ro] = l0; *(ushortx8*)&PL[ro + 8] = l1;
}

// =======================================================================
// RMSNorm: f32 row -> hi/lo bf16 planes. One block per row, D=1280.
// =======================================================================
__global__ __launch_bounds__(256) void rmsnorm_kernel(
    const float* __restrict__ x, const float* __restrict__ w,
    unsigned short* __restrict__ yh, unsigned short* __restrict__ yl)
{
  const int row = blockIdx.x;
  const float* xr = x + (size_t)row * 1280;
  float ss = 0.f;
  for (int i = threadIdx.x; i < 1280; i += 256){ float v = xr[i]; ss = fmaf(v, v, ss); }
  for (int o = 32; o > 0; o >>= 1) ss += __shfl_down(ss, o);
  __shared__ float wsum[4];
  __shared__ float snorm;
  if ((threadIdx.x & 63) == 0) wsum[threadIdx.x >> 6] = ss;
  __syncthreads();
  if (threadIdx.x == 0){
    float t = wsum[0] + wsum[1] + wsum[2] + wsum[3];
    snorm = 1.0f / sqrtf(t * (1.0f / 1280.0f) + 1e-6f);
  }
  __syncthreads();
  float s = snorm;
  for (int i = threadIdx.x; i < 1280; i += 256){
    float v = xr[i] * s * w[i];
    unsigned short h, l; split_bf(v, h, l);
    yh[(size_t)row * 1280 + i] = h;
    yl[(size_t)row * 1280 + i] = l;
  }
}

// =======================================================================
// Patch gather (window perm folded) -> hi/lo planes [1024][1216]
// =======================================================================
__global__ __launch_bounds__(256) void gather_x_kernel(
    const float* __restrict__ img, const int* __restrict__ win,
    unsigned short* __restrict__ Xh, unsigned short* __restrict__ Xl)
{
  int idx = blockIdx.x * 256 + threadIdx.x;
  if (idx >= 1024 * 1216) return;
  int s = idx / 1216, f = idx - s * 1216;
  float val = 0.f;
  if (f < 1176){
    int sp = (win[s >> 2] << 2) | (s & 3);
    int i0 = sp >> 6, r = sp & 63;
    int i3 = r >> 2, rr = r & 3, i1 = rr >> 1, i4 = rr & 1;
    int c  = f / 392, f2 = f - c * 392;
    int f3 = f2 % 196;
    int ph = f3 / 14, pw2 = f3 - ph * 14;
    int hp = (i0 * 2 + i1) * 14 + ph, wp = (i3 * 2 + i4) * 14 + pw2;
    val = img[((size_t)c * 448 + hp) * 448 + wp];
  }
  unsigned short h, l; split_bf(val, h, l);
  Xh[idx] = h; Xl[idx] = l;
}

__global__ __launch_bounds__(256) void rope_tables_kernel(
    const float* __restrict__ rpe, const int* __restrict__ win,
    float* __restrict__ cosb, float* __restrict__ sinb)
{
  int idx = blockIdx.x * 256 + threadIdx.x;
  if (idx >= 1024 * 80) return;
  int s = idx / 80, d = idx - s * 80;
  int src = (win[s >> 2] << 2) | (s & 3);
  float ang = rpe[src * 40 + (d % 40)];
  cosb[idx] = cosf(ang);
  sinb[idx] = sinf(ang);
}

// qkv f32 -> rope'd Q (pre-scaled), K as hi/lo planes [16][1024][128] (d-pad 0)
__global__ __launch_bounds__(256) void rope_qk_kernel(
    const float* __restrict__ qkv, const float* __restrict__ cosb, const float* __restrict__ sinb,
    unsigned short* __restrict__ Qh, unsigned short* __restrict__ Ql,
    unsigned short* __restrict__ Kh, unsigned short* __restrict__ Kl)
{
  int idx = blockIdx.x * 256 + threadIdx.x;
  if (idx >= 1024 * 16 * 128) return;
  int s = idx >> 11;
  int rem = idx & 2047;
  int h = rem >> 7, d = rem & 127;
  size_t o = ((size_t)h * 1024 + s) * 128 + d;
  if (d >= 80){ Qh[o] = 0; Ql[o] = 0; Kh[o] = 0; Kl[o] = 0; return; }
  const float* base = qkv + (size_t)s * 3840;
  float qv = base[h * 80 + d], kv = base[1280 + h * 80 + d];
  float qo = (d < 40) ? -base[h * 80 + d + 40] : base[h * 80 + d - 40];
  float ko = (d < 40) ? -base[1280 + h * 80 + d + 40] : base[1280 + h * 80 + d - 40];
  float cc = cosb[s * 80 + d], sn = sinb[s * 80 + d];
  float q = (qv * cc + qo * sn) * 0.11180339887498949f;
  float k = kv * cc + ko * sn;
  unsigned short hh, ll;
  split_bf(q, hh, ll); Qh[o] = hh; Ql[o] = ll;
  split_bf(k, hh, ll); Kh[o] = hh; Kl[o] = ll;
}

// V transpose: qkv f32 -> VT planes [16][80][1024]
__global__ __launch_bounds__(256) void vt_kernel(
    const float* __restrict__ qkv,
    unsigned short* __restrict__ Vth, unsigned short* __restrict__ Vtl)
{
  __shared__ float T[64][81];
  const int h = blockIdx.y, s0 = blockIdx.x * 64;
  for (int c = threadIdx.x; c < 64 * 80; c += 256){
    int sl = c / 80, d = c - sl * 80;
    T[sl][d] = qkv[(size_t)(s0 + sl) * 3840 + 2560 + h * 80 + d];
  }
  __syncthreads();
  for (int c = threadIdx.x; c < 80 * 64; c += 256){
    int d = c >> 6, sl = c & 63;
    unsigned short hh, ll; split_bf(T[sl][d], hh, ll);
    size_t o = ((size_t)h * 80 + d) * 1024 + s0 + sl;
    Vth[o] = hh; Vtl[o] = ll;
  }
}

// concat gate_b/up_b interleaved -> [8][6912]
__global__ __launch_bounds__(256) void concat_bias_kernel(
    const float* __restrict__ gb, const float* __restrict__ ub, float* __restrict__ out)
{
  int idx = blockIdx.x * 256 + threadIdx.x;
  if (idx >= 8 * 6912) return;
  int l = idx / 6912, j = idx - l * 6912;
  out[idx] = (j & 1) ? ub[l * 3456 + (j >> 1)] : gb[l * 3456 + (j >> 1)];
}

// =======================================================================
// MFMA flash attention. block = (q-tile 64, head), 4 waves, KVBLK=32.
// Q pre-scaled, planes stride 128 (d-pad zero). K staged swizzled;
// VT staged swizzled; P through LDS for PV A-frags. Split-bf16 (3 MFMA).
// =======================================================================
template<bool FULL>
__global__ __launch_bounds__(256) void attn_mfma(
    const unsigned short* __restrict__ Qh, const unsigned short* __restrict__ Ql,
    const unsigned short* __restrict__ Kh, const unsigned short* __restrict__ Kl,
    const unsigned short* __restrict__ Vth, const unsigned short* __restrict__ Vtl,
    unsigned short* __restrict__ Oh, unsigned short* __restrict__ Ol)
{
  __shared__ unsigned short KT[2][2][32 * 128];  // 8KB/plane/buf -> 32KB
  __shared__ unsigned short VS[2][2][80 * 32];   // 5KB/plane/buf -> 20KB
  __shared__ unsigned short PS[2][64 * 40];      // 5.12KB/plane -> 10.24KB
  const int tid = threadIdx.x, lane = tid & 63, wv = tid >> 6;
  const int qb = blockIdx.x, h = blockIdx.y;
  const int fr = lane & 15, kg = lane >> 4;

  // Q A-frags, registers (rows wv*16+fr of q-tile)
  short8 qfh[3], qfl[3];
  {
    size_t qbase = ((size_t)h * 1024 + qb * 64 + wv * 16 + fr) * 128;
    #pragma unroll
    for (int ks = 0; ks < 3; ks++){
      qfh[ks] = *(const short8*)(Qh + qbase + ks * 32 + kg * 8);
      qfl[ks] = *(const short8*)(Ql + qbase + ks * 32 + kg * 8);
    }
  }
  float m_r[4], l_r[4];
  #pragma unroll
  for (int r = 0; r < 4; r++){ m_r[r] = -3e38f; l_r[r] = 0.f; }
  floatx4 oa[5];
  #pragma unroll
  for (int nb = 0; nb < 5; nb++) oa[nb] = 0.f;

  const int nt  = FULL ? 32 : 2;
  const int kt0 = FULL ? 0 : qb * 2;

  auto stageK = [&](int buf, int kt){
    #pragma unroll
    for (int p = 0; p < 2; p++){
      int lin = p * 256 + tid;
      int row = lin >> 4, gg = (lin & 15) ^ (row & 7);
      size_t go = ((size_t)h * 1024 + kt * 32 + row) * 128 + gg * 8;
      gld_lds16(Kh + go, &KT[buf][0][(p * 256 + wv * 64) * 8]);
      gld_lds16(Kl + go, &KT[buf][1][(p * 256 + wv * 64) * 8]);
    }
    #pragma unroll
    for (int p = 0; p < 2; p++){
      int lin = p * 256 + tid;
      if (lin < 320){
        int row = lin >> 2, gg = (lin & 3) ^ (row & 3);
        size_t go = ((size_t)h * 80 + row) * 1024 + kt * 32 + gg * 8;
        gld_lds16(Vth + go, &VS[buf][0][(p * 256 + wv * 64) * 8]);
        gld_lds16(Vtl + go, &VS[buf][1][(p * 256 + wv * 64) * 8]);
      }
    }
  };

  stageK(0, kt0);
  __syncthreads();
  for (int t = 0; t < nt; t++){
    const int buf = t & 1;
    if (t + 1 < nt) stageK(buf ^ 1, kt0 + t + 1);
    // ---- QK^T (strip 16 rows x 32 cols)
    floatx4 accS[2];
    accS[0] = 0.f; accS[1] = 0.f;
    #pragma unroll
    for (int c = 0; c < 2; c++){
      #pragma unroll
      for (int ks = 0; ks < 3; ks++){
        int row = c * 16 + fr;
        int off = row * 256 + ((ks * 64 + kg * 16) ^ ((row & 7) << 4));
        short8 kh_ = *(const short8*)((const char*)&KT[buf][0][0] + off);
        short8 kl_ = *(const short8*)((const char*)&KT[buf][1][0] + off);
        accS[c] = mfma(qfl[ks], kh_, accS[c]);
        accS[c] = mfma(qfh[ks], kl_, accS[c]);
        accS[c] = mfma(qfh[ks], kh_, accS[c]);
      }
    }
    // ---- online softmax (rows kg*4+r of strip; cols across fr and c)
    float corr[4], ps_[4];
    #pragma unroll
    for (int r = 0; r < 4; r++){
      float v = fmaxf(accS[0][r], accS[1][r]);
      v = fmaxf(v, __shfl_xor(v, 1)); v = fmaxf(v, __shfl_xor(v, 2));
      v = fmaxf(v, __shfl_xor(v, 4)); v = fmaxf(v, __shfl_xor(v, 8));
      float mn = fmaxf(m_r[r], v);
      corr[r] = __expf(m_r[r] - mn);
      m_r[r] = mn;
      ps_[r] = 0.f;
    }
    #pragma unroll
    for (int c = 0; c < 2; c++)
      #pragma unroll
      for (int r = 0; r < 4; r++){
        float p = __expf(accS[c][r] - m_r[r]);
        ps_[r] += p;
        unsigned short ph, pl; split_bf(p, ph, pl);
        int po = (wv * 16 + kg * 4 + r) * 40 + c * 16 + fr;
        PS[0][po] = ph;
        PS[1][po] = pl;
      }
    #pragma unroll
    for (int r = 0; r < 4; r++){
      float v = ps_[r];
      v += __shfl_xor(v, 1); v += __shfl_xor(v, 2);
      v += __shfl_xor(v, 4); v += __shfl_xor(v, 8);
      l_r[r] = l_r[r] * corr[r] + v;
      #pragma unroll
      for (int nb = 0; nb < 5; nb++) oa[nb][r] *= corr[r];
    }
    // ---- PV (A = P strip rows fr; B = VT)
    {
      int poff = (wv * 16 + fr) * 80 + kg * 16;  // bytes (ld=40 elems)
      short8 pah = *(const short8*)((const char*)&PS[0][0] + poff);
      short8 pal = *(const short8*)((const char*)&PS[1][0] + poff);
      #pragma unroll
      for (int nb = 0; nb < 5; nb++){
        int row = nb * 16 + fr;
        int off = row * 64 + ((kg * 16) ^ ((row & 3) << 4));
        short8 vh_ = *(const short8*)((const char*)&VS[buf][0][0] + off);
        short8 vl_ = *(const short8*)((const char*)&VS[buf][1][0] + off);
        oa[nb] = mfma(pal, vh_, oa[nb]);
        oa[nb] = mfma(pah, vl_, oa[nb]);
        oa[nb] = mfma(pah, vh_, oa[nb]);
      }
    }
    __syncthreads();
  }
  // ---- epilogue
  float linv[4];
  #pragma unroll
  for (int r = 0; r < 4; r++) linv[r] = 1.f / l_r[r];
  #pragma unroll
  for (int nb = 0; nb < 5; nb++)
    #pragma unroll
    for (int r = 0; r < 4; r++){
      float v = oa[nb][r] * linv[r];
      unsigned short hh, ll; split_bf(v, hh, ll);
      size_t o = (size_t)(qb * 64 + wv * 16 + kg * 4 + r) * 1280 + h * 80 + nb * 16 + fr;
      Oh[o] = hh; Ol[o] = ll;
    }
}

// =======================================================================
extern "C" void kernel_launch(void* const* d_in, const int* in_sizes, int n_in,
                              void* d_out, int out_size, void* d_ws, size_t ws_size,
                              hipStream_t stream)
{
  (void)in_sizes; (void)n_in; (void)out_size;
  const float* images  = (const float*)d_in[0];
  const int*   win     = (const int*)  d_in[1];
  const float* rpe     = (const float*)d_in[3];
  const float* patch_w = (const float*)d_in[6];
  const float* ln1_w   = (const float*)d_in[7];
  const float* ln2_w   = (const float*)d_in[8];
  const float* qkv_w   = (const float*)d_in[9];
  const float* qkv_b   = (const float*)d_in[10];
  const float* proj_w  = (const float*)d_in[11];
  const float* proj_b  = (const float*)d_in[12];
  const float* gate_w  = (const float*)d_in[13];
  const float* gate_b  = (const float*)d_in[14];
  const float* up_w    = (const float*)d_in[15];
  const float* up_b    = (const float*)d_in[16];
  const float* down_w  = (const float*)d_in[17];
  const float* down_b  = (const float*)d_in[18];
  const float* lnq_w   = (const float*)d_in[19];
  const float* m1_w    = (const float*)d_in[20];
  const float* m1_b    = (const float*)d_in[21];
  const float* m2_w    = (const float*)d_in[22];
  const float* m2_b    = (const float*)d_in[23];

  char* ws = (char*)d_ws;
  size_t off = 0;
  auto alloc = [&](size_t b){ size_t o = off; off += (b + 255) & ~(size_t)255; return o; };
  unsigned short* WPH = (unsigned short*)(ws + alloc(13107200ull * 2));
  unsigned short* WPL = (unsigned short*)(ws + alloc(13107200ull * 2));
  unsigned short* Xh  = (unsigned short*)(ws + alloc(1024ull * 1216 * 2));
  unsigned short* Xl  = (unsigned short*)(ws + alloc(1024ull * 1216 * 2));
  unsigned short* ANh = (unsigned short*)(ws + alloc(1024ull * 1280 * 2));
  unsigned short* ANl = (unsigned short*)(ws + alloc(1024ull * 1280 * 2));
  float* H    = (float*)(ws + alloc(1024ull * 1280 * 4));
  float* QKV  = (float*)(ws + alloc(1024ull * 3840 * 4));
  unsigned short* Qph = (unsigned short*)(ws + alloc(16ull * 1024 * 128 * 2));
  unsigned short* Qpl = (unsigned short*)(ws + alloc(16ull * 1024 * 128 * 2));
  unsigned short* Kph = (unsigned short*)(ws + alloc(16ull * 1024 * 128 * 2));
  unsigned short* Kpl = (unsigned short*)(ws + alloc(16ull * 1024 * 128 * 2));
  unsigned short* Vth = (unsigned short*)(ws + alloc(16ull * 80 * 1024 * 2));
  unsigned short* Vtl = (unsigned short*)(ws + alloc(16ull * 80 * 1024 * 2));
  unsigned short* Ohh = (unsigned short*)(ws + alloc(1024ull * 1280 * 2));
  unsigned short* Oll = (unsigned short*)(ws + alloc(1024ull * 1280 * 2));
  unsigned short* DAh = (unsigned short*)(ws + alloc(1024ull * 3456 * 2));
  unsigned short* DAl = (unsigned short*)(ws + alloc(1024ull * 3456 * 2));
  unsigned short* G1h = (unsigned short*)(ws + alloc(256ull * 5120 * 2));
  unsigned short* G1l = (unsigned short*)(ws + alloc(256ull * 5120 * 2));
  float* COSb = (float*)(ws + alloc(1024ull * 80 * 4));
  float* SINb = (float*)(ws + alloc(1024ull * 80 * 4));
  float* BGU  = (float*)(ws + alloc(8ull * 6912 * 4));
  if (off > ws_size) return;

  gather_x_kernel   <<<4864, 256, 0, stream>>>(images, win, Xh, Xl);
  rope_tables_kernel<<<320,  256, 0, stream>>>(rpe, win, COSb, SINb);
  concat_bias_kernel<<<216,  256, 0, stream>>>(gate_b, up_b, BGU);

  // patch embed: X(1024x1216 planes) @ PW^T -> H f32
  convert_w_kernel<<<dim3(19, 20), 256, 0, stream>>>(patch_w, WPH, WPL, 1176, 1280, 0, 1216, 0, 1, 0);
  gemm_bf2<128, 64, 0><<<dim3(20, 8), 256, 0, stream>>>(
      Xh, Xl, WPH, WPL, nullptr, nullptr, H, nullptr, nullptr, nullptr, 1216, 1280, 0);

  for (int i = 0; i < 8; i++){
    rmsnorm_kernel<<<1024, 256, 0, stream>>>(H, ln1_w + (size_t)i * 1280, ANh, ANl);
    convert_w_kernel<<<dim3(20, 60), 256, 0, stream>>>(
        qkv_w + (size_t)i * 1280 * 3840, WPH, WPL, 1280, 3840, 0, 1280, 0, 1, 0);
    gemm_bf2<128, 128, 0><<<dim3(30, 8), 256, 0, stream>>>(
        ANh, ANl, WPH, WPL, qkv_b + (size_t)i * 3840, nullptr,
        QKV, nullptr, nullptr, nullptr, 1280, 3840, 0);
    rope_qk_kernel<<<8192, 256, 0, stream>>>(QKV, COSb, SINb, Qph, Qpl, Kph, Kpl);
    vt_kernel<<<dim3(16, 16), 256, 0, stream>>>(QKV, Vth, Vtl);
    if (i == 3 || i == 7)
      attn_mfma<true ><<<dim3(16, 16), 256, 0, stream>>>(Qph, Qpl, Kph, Kpl, Vth, Vtl, Ohh, Oll);
    else
      attn_mfma<false><<<dim3(16, 16), 256, 0, stream>>>(Qph, Qpl, Kph, Kpl, Vth, Vtl, Ohh, Oll);
    convert_w_kernel<<<dim3(20, 20), 256, 0, stream>>>(
        proj_w + (size_t)i * 1280 * 1280, WPH, WPL, 1280, 1280, 0, 1280, 0, 1, 0);
    gemm_bf2<128, 64, 1><<<dim3(20, 8), 256, 0, stream>>>(
        Ohh, Oll, WPH, WPL, proj_b + (size_t)i * 1280, H,
        H, nullptr, nullptr, nullptr, 1280, 1280, 0);
    rmsnorm_kernel<<<1024, 256, 0, stream>>>(H, ln2_w + (size_t)i * 1280, ANh, ANl);
    convert_w_kernel<<<dim3(20, 54), 256, 0, stream>>>(
        gate_w + (size_t)i * 1280 * 3456, WPH, WPL, 1280, 3456, 0, 1280, 0, 2, 0);
    convert_w_kernel<<<dim3(20, 54), 256, 0, stream>>>(
        up_w + (size_t)i * 1280 * 3456, WPH, WPL, 1280, 3456, 0, 1280, 0, 2, 1);
    gemm_bf2<128, 128, 4><<<dim3(54, 8), 256, 0, stream>>>(
        ANh, ANl, WPH, WPL, BGU + (size_t)i * 6912, nullptr,
        nullptr, DAh, DAl, nullptr, 1280, 3456, 0);
    convert_w_kernel<<<dim3(54, 20), 256, 0, stream>>>(
        down_w + (size_t)i * 3456 * 1280, WPH, WPL, 3456, 1280, 0, 3456, 0, 1, 0);
    gemm_bf2<128, 64, 1><<<dim3(20, 8), 256, 0, stream>>>(
        DAh, DAl, WPH, WPL, down_b + (size_t)i * 1280, H,
        H, nullptr, nullptr, nullptr, 3456, 1280, 0);
  }

  // merger
  rmsnorm_kernel<<<1024, 256, 0, stream>>>(H, lnq_w, ANh, ANl);
  for (int hh = 0; hh < 2; hh++){
    convert_w_kernel<<<dim3(80, 40), 256, 0, stream>>>(
        m1_w, WPH, WPL, 5120, 5120, hh * 2560, 5120, 0, 1, 0);
    gemm_bf2<64, 64, 2><<<dim3(40, 4), 256, 0, stream>>>(
        ANh, ANl, WPH, WPL, m1_b + hh * 2560, nullptr,
        nullptr, G1h, G1l, nullptr, 5120, 5120, hh * 2560);
  }
  for (int hh = 0; hh < 2; hh++){
    convert_w_kernel<<<dim3(80, 28), 256, 0, stream>>>(
        m2_w, WPH, WPL, 5120, 3584, hh * 1792, 5120, 0, 1, 0);
    gemm_bf2<64, 64, 3><<<dim3(28, 4), 256, 0, stream>>>(
        G1h, G1l, WPH, WPL, m2_b + hh * 1792, nullptr,
        (float*)d_out, nullptr, nullptr, win, 5120, 3584, hh * 1792);
  }
}

// Round 4
// 2884.826 us; speedup vs baseline: 2.8598x; 1.0996x over previous
//
#include <hip/hip_runtime.h>
#include <math.h>

typedef float  floatx4  __attribute__((ext_vector_type(4)));
typedef short  short8   __attribute__((ext_vector_type(8)));
typedef unsigned short ushortx4 __attribute__((ext_vector_type(4)));
typedef unsigned short ushortx8 __attribute__((ext_vector_type(8)));

// ---------- bf16 helpers (RNE) ----------
__device__ inline unsigned short f2bf(float x){
  unsigned u = __float_as_uint(x);
  u += 0x7FFFu + ((u >> 16) & 1u);
  return (unsigned short)(u >> 16);
}
__device__ inline float bf2f(unsigned short b){ return __uint_as_float(((unsigned)b) << 16); }
__device__ inline void split_bf(float x, unsigned short& h, unsigned short& l){
  h = f2bf(x); l = f2bf(x - bf2f(h));
}

// ---------- MFMA 16x16x32 bf16 ----------
// A-frag: lane l holds A[l&15][(l>>4)*8+j]; B-frag: lane l holds B[(l>>4)*8+j][l&15]
// C/D: lane l reg r = D[(l>>4)*4+r][l&15]   (verified rounds 1-3)
__device__ inline floatx4 mfma(short8 a, short8 b, floatx4 c){
  return __builtin_amdgcn_mfma_f32_16x16x32_bf16(a, b, c, 0, 0, 0);
}

// ---------- async global->LDS, 16B per lane ----------
__device__ inline void gld_lds16(const void* g, void* l){
  __builtin_amdgcn_global_load_lds(
      (const __attribute__((address_space(1))) unsigned int*)g,
      (__attribute__((address_space(3))) unsigned int*)l, 16, 0, 0);
}

// =======================================================================
// Dual-plane bf16 GEMM: out[M,N] = (Ah+Al)[M,K] @ (Wh+Wl)^T[N,K]
// Double-buffered LDS, global_load_lds staging, XOR-swizzled granules.
// KSPLIT>1: blockIdx.z handles K-range [z*K/KSPLIT, ...), writes f32
//           partials to part[(z*Mtot+row)*N + col]; epilogue in reduce_k.
// KSPLIT==1 epilogue modes:
//   MODE 0: outf = acc + bias
//   MODE 4: interleaved gate/up -> planes = silu(g)*u at col>>1
// =======================================================================
template<int BM, int BN, int MODE, int KSPLIT>
__global__ __launch_bounds__(256) void gemm_bf2(
    const unsigned short* __restrict__ Ah, const unsigned short* __restrict__ Al,
    const unsigned short* __restrict__ Wh, const unsigned short* __restrict__ Wl,
    const float* __restrict__ bias,
    float* __restrict__ outf, unsigned short* __restrict__ outh,
    unsigned short* __restrict__ outl,
    int K, int Nout, int Mtot, float* __restrict__ part)
{
  __shared__ unsigned short SA[2][2][BM*32];
  __shared__ unsigned short SW[2][2][BN*32];
  const int tid = threadIdx.x, lane = tid & 63, wv = tid >> 6;
  const int wm = wv >> 1, wn = wv & 1;
  const int m0 = blockIdx.y * BM, n0 = blockIdx.x * BN;
  const int kbase = (KSPLIT > 1) ? blockIdx.z * (K / KSPLIT) : 0;
  constexpr int MR = BM / 32, NR = BN / 32;
  floatx4 acc[MR][NR];
  #pragma unroll
  for (int mr = 0; mr < MR; mr++)
    #pragma unroll
    for (int nr = 0; nr < NR; nr++) acc[mr][nr] = 0.f;
  const int fr = lane & 15, kg = lane >> 4;

  auto stage = [&](int buf, int k0){
    #pragma unroll
    for (int p = 0; p < (BM * 4) / 256; p++){
      int lin = p * 256 + tid;
      int row = lin >> 2, gg = (lin & 3) ^ ((row >> 1) & 3);
      size_t go = (size_t)(m0 + row) * K + kbase + k0 + gg * 8;
      gld_lds16(Ah + go, &SA[buf][0][(p * 256 + wv * 64) * 8]);
      gld_lds16(Al + go, &SA[buf][1][(p * 256 + wv * 64) * 8]);
    }
    #pragma unroll
    for (int p = 0; p < (BN * 4) / 256; p++){
      int lin = p * 256 + tid;
      int row = lin >> 2, gg = (lin & 3) ^ ((row >> 1) & 3);
      size_t go = (size_t)(n0 + row) * K + kbase + k0 + gg * 8;
      gld_lds16(Wh + go, &SW[buf][0][(p * 256 + wv * 64) * 8]);
      gld_lds16(Wl + go, &SW[buf][1][(p * 256 + wv * 64) * 8]);
    }
  };

  stage(0, 0);
  __syncthreads();
  const int nt = (K / KSPLIT) >> 5;
  for (int t = 0; t < nt; t++){
    const int buf = t & 1;
    if (t + 1 < nt) stage(buf ^ 1, (t + 1) << 5);
    short8 ah[MR], al[MR], wh[NR], wl[NR];
    #pragma unroll
    for (int mr = 0; mr < MR; mr++){
      int r = wm * (BM / 2) + mr * 16 + fr;
      int off = r * 64 + ((kg ^ ((r >> 1) & 3)) << 4);
      ah[mr] = *(const short8*)((const char*)&SA[buf][0][0] + off);
      al[mr] = *(const short8*)((const char*)&SA[buf][1][0] + off);
    }
    #pragma unroll
    for (int nr = 0; nr < NR; nr++){
      int r = wn * (BN / 2) + nr * 16 + fr;
      int off = r * 64 + ((kg ^ ((r >> 1) & 3)) << 4);
      wh[nr] = *(const short8*)((const char*)&SW[buf][0][0] + off);
      wl[nr] = *(const short8*)((const char*)&SW[buf][1][0] + off);
    }
    #pragma unroll
    for (int mr = 0; mr < MR; mr++)
      #pragma unroll
      for (int nr = 0; nr < NR; nr++){
        acc[mr][nr] = mfma(al[mr], wh[nr], acc[mr][nr]);
        acc[mr][nr] = mfma(ah[mr], wl[nr], acc[mr][nr]);
        acc[mr][nr] = mfma(ah[mr], wh[nr], acc[mr][nr]);
      }
    __syncthreads();
  }
  #pragma unroll
  for (int mr = 0; mr < MR; mr++)
    #pragma unroll
    for (int nr = 0; nr < NR; nr++){
      int np = n0 + wn * (BN / 2) + nr * 16 + fr;
      #pragma unroll
      for (int e = 0; e < 4; e++){
        int row = m0 + wm * (BM / 2) + mr * 16 + kg * 4 + e;
        float v = acc[mr][nr][e];
        if (KSPLIT > 1){
          part[((size_t)blockIdx.z * Mtot + row) * Nout + np] = v;
        } else {
          v += bias ? bias[np] : 0.f;
          if (MODE == 0) outf[(size_t)row * Nout + np] = v;
          if (MODE == 4){
            float pv = __shfl_xor(v, 1);
            if (!(fr & 1)){
              float dv = v / (1.f + __expf(-v)) * pv;
              unsigned short hh, ll; split_bf(dv, hh, ll);
              outh[(size_t)row * (Nout >> 1) + (np >> 1)] = hh;
              outl[(size_t)row * (Nout >> 1) + (np >> 1)] = ll;
            }
          }
        }
      }
    }
}

// =======================================================================
// Split-K reduce + epilogue. part[z][M][N] f32, fixed-order sum.
// MODE 0: outf = sum + bias
// MODE 1: outf = sum + bias + res (res may alias outf)
// MODE 2: planes = gelu_exact(sum + bias)
// MODE 3: outf[rowmap[row]*N + col] = sum + bias
// =======================================================================
template<int MODE>
__global__ __launch_bounds__(256) void reduce_k(
    const float* __restrict__ part, int Z, int M, int N,
    const float* __restrict__ bias, const float* __restrict__ res,
    float* __restrict__ outf, unsigned short* __restrict__ outh,
    unsigned short* __restrict__ outl, const int* __restrict__ rowmap)
{
  int idx4 = (blockIdx.x * 256 + threadIdx.x) * 4;
  if (idx4 >= M * N) return;
  int row = idx4 / N, col = idx4 - row * N;
  floatx4 v = *(const floatx4*)(part + (size_t)row * N + col);
  for (int z = 1; z < Z; z++){
    floatx4 p = *(const floatx4*)(part + ((size_t)z * M + row) * N + col);
    v[0] += p[0]; v[1] += p[1]; v[2] += p[2]; v[3] += p[3];
  }
  if (bias){
    floatx4 b = *(const floatx4*)(bias + col);
    v[0] += b[0]; v[1] += b[1]; v[2] += b[2]; v[3] += b[3];
  }
  if (MODE == 1){
    floatx4 r = *(const floatx4*)(res + (size_t)row * N + col);
    v[0] += r[0]; v[1] += r[1]; v[2] += r[2]; v[3] += r[3];
  }
  if (MODE == 0 || MODE == 1){
    *(floatx4*)(outf + (size_t)row * N + col) = v;
  } else if (MODE == 2){
    ushortx4 hh, ll;
    #pragma unroll
    for (int j = 0; j < 4; j++){
      float g = 0.5f * v[j] * (1.f + erff(v[j] * 0.70710678118654752f));
      unsigned short h, l; split_bf(g, h, l);
      hh[j] = h; ll[j] = l;
    }
    *(ushortx4*)(outh + (size_t)row * N + col) = hh;
    *(ushortx4*)(outl + (size_t)row * N + col) = ll;
  } else if (MODE == 3){
    *(floatx4*)(outf + (size_t)rowmap[row] * N + col) = v;
  }
}

// =======================================================================
// Weight convert: W f32 [K][Nstride] (cols at n_src0) -> transposed hi/lo
// planes at row (plane_row0 + n*row_mul + row_add), [.][Kpad], zero-pad k>=K
// =======================================================================
__global__ __launch_bounds__(256) void convert_w_kernel(
    const float* __restrict__ W, unsigned short* __restrict__ PH,
    unsigned short* __restrict__ PL,
    int K, int Nstride, int n_src0, int Kpad, int plane_row0,
    int row_mul, int row_add)
{
  __shared__ float T[64][68];
  const int tid = threadIdx.x;
  const int k0 = blockIdx.x * 64, n0 = blockIdx.y * 64;
  const int kr = tid >> 4, nc = (tid & 15) << 2;
  #pragma unroll
  for (int p = 0; p < 4; p++){
    int k = k0 + p * 16 + kr;
    floatx4 v = {0.f, 0.f, 0.f, 0.f};
    if (k < K) v = *(const floatx4*)(W + (size_t)k * Nstride + n_src0 + n0 + nc);
    *(floatx4*)&T[p * 16 + kr][nc] = v;
  }
  __syncthreads();
  const int n = tid >> 2, kc = (tid & 3) << 4;
  ushortx8 h0, h1, l0, l1;
  #pragma unroll
  for (int j = 0; j < 8; j++){
    unsigned short h, l;
    split_bf(T[kc + j][n], h, l);       h0[j] = h; l0[j] = l;
    split_bf(T[kc + 8 + j][n], h, l);   h1[j] = h; l1[j] = l;
  }
  size_t ro = (size_t)(plane_row0 + (n0 + n) * row_mul + row_add) * Kpad + k0 + kc;
  *(ushortx8*)&PH[ro] = h0; *(ushortx8*)&PH[ro + 8] = h1;
  *(ushortx8*)&PL[ro] = l0; *(ushortx8*)&PL[ro + 8] = l1;
}

// =======================================================================
// RMSNorm: f32 row -> hi/lo bf16 planes. One block per row, D=1280.
// =======================================================================
__global__ __launch_bounds__(256) void rmsnorm_kernel(
    const float* __restrict__ x, const float* __restrict__ w,
    unsigned short* __restrict__ yh, unsigned short* __restrict__ yl)
{
  const int row = blockIdx.x;
  const float* xr = x + (size_t)row * 1280;
  float ss = 0.f;
  for (int i = threadIdx.x; i < 1280; i += 256){ float v = xr[i]; ss = fmaf(v, v, ss); }
  for (int o = 32; o > 0; o >>= 1) ss += __shfl_down(ss, o);
  __shared__ float wsum[4];
  __shared__ float snorm;
  if ((threadIdx.x & 63) == 0) wsum[threadIdx.x >> 6] = ss;
  __syncthreads();
  if (threadIdx.x == 0){
    float t = wsum[0] + wsum[1] + wsum[2] + wsum[3];
    snorm = 1.0f / sqrtf(t * (1.0f / 1280.0f) + 1e-6f);
  }
  __syncthreads();
  float s = snorm;
  for (int i = threadIdx.x; i < 1280; i += 256){
    float v = xr[i] * s * w[i];
    unsigned short h, l; split_bf(v, h, l);
    yh[(size_t)row * 1280 + i] = h;
    yl[(size_t)row * 1280 + i] = l;
  }
}

// =======================================================================
// Patch gather (window perm folded) -> hi/lo planes [1024][1216]
// =======================================================================
__global__ __launch_bounds__(256) void gather_x_kernel(
    const float* __restrict__ img, const int* __restrict__ win,
    unsigned short* __restrict__ Xh, unsigned short* __restrict__ Xl)
{
  int idx = blockIdx.x * 256 + threadIdx.x;
  if (idx >= 1024 * 1216) return;
  int s = idx / 1216, f = idx - s * 1216;
  float val = 0.f;
  if (f < 1176){
    int sp = (win[s >> 2] << 2) | (s & 3);
    int i0 = sp >> 6, r = sp & 63;
    int i3 = r >> 2, rr = r & 3, i1 = rr >> 1, i4 = rr & 1;
    int c  = f / 392, f2 = f - c * 392;
    int f3 = f2 % 196;
    int ph = f3 / 14, pw2 = f3 - ph * 14;
    int hp = (i0 * 2 + i1) * 14 + ph, wp = (i3 * 2 + i4) * 14 + pw2;
    val = img[((size_t)c * 448 + hp) * 448 + wp];
  }
  unsigned short h, l; split_bf(val, h, l);
  Xh[idx] = h; Xl[idx] = l;
}

__global__ __launch_bounds__(256) void rope_tables_kernel(
    const float* __restrict__ rpe, const int* __restrict__ win,
    float* __restrict__ cosb, float* __restrict__ sinb)
{
  int idx = blockIdx.x * 256 + threadIdx.x;
  if (idx >= 1024 * 80) return;
  int s = idx / 80, d = idx - s * 80;
  int src = (win[s >> 2] << 2) | (s & 3);
  float ang = rpe[src * 40 + (d % 40)];
  cosb[idx] = cosf(ang);
  sinb[idx] = sinf(ang);
}

// qkv f32 -> rope'd Q (pre-scaled), K as hi/lo planes [16][1024][128] (d-pad 0)
__global__ __launch_bounds__(256) void rope_qk_kernel(
    const float* __restrict__ qkv, const float* __restrict__ cosb, const float* __restrict__ sinb,
    unsigned short* __restrict__ Qh, unsigned short* __restrict__ Ql,
    unsigned short* __restrict__ Kh, unsigned short* __restrict__ Kl)
{
  int idx = blockIdx.x * 256 + threadIdx.x;
  if (idx >= 1024 * 16 * 128) return;
  int s = idx >> 11;
  int rem = idx & 2047;
  int h = rem >> 7, d = rem & 127;
  size_t o = ((size_t)h * 1024 + s) * 128 + d;
  if (d >= 80){ Qh[o] = 0; Ql[o] = 0; Kh[o] = 0; Kl[o] = 0; return; }
  const float* base = qkv + (size_t)s * 3840;
  float qv = base[h * 80 + d], kv = base[1280 + h * 80 + d];
  float qo = (d < 40) ? -base[h * 80 + d + 40] : base[h * 80 + d - 40];
  float ko = (d < 40) ? -base[1280 + h * 80 + d + 40] : base[1280 + h * 80 + d - 40];
  float cc = cosb[s * 80 + d], sn = sinb[s * 80 + d];
  float q = (qv * cc + qo * sn) * 0.11180339887498949f;
  float k = kv * cc + ko * sn;
  unsigned short hh, ll;
  split_bf(q, hh, ll); Qh[o] = hh; Ql[o] = ll;
  split_bf(k, hh, ll); Kh[o] = hh; Kl[o] = ll;
}

// V transpose: qkv f32 -> VT planes [16][80][1024]
__global__ __launch_bounds__(256) void vt_kernel(
    const float* __restrict__ qkv,
    unsigned short* __restrict__ Vth, unsigned short* __restrict__ Vtl)
{
  __shared__ float T[64][81];
  const int h = blockIdx.y, s0 = blockIdx.x * 64;
  for (int c = threadIdx.x; c < 64 * 80; c += 256){
    int sl = c / 80, d = c - sl * 80;
    T[sl][d] = qkv[(size_t)(s0 + sl) * 3840 + 2560 + h * 80 + d];
  }
  __syncthreads();
  for (int c = threadIdx.x; c < 80 * 64; c += 256){
    int d = c >> 6, sl = c & 63;
    unsigned short hh, ll; split_bf(T[sl][d], hh, ll);
    size_t o = ((size_t)h * 80 + d) * 1024 + s0 + sl;
    Vth[o] = hh; Vtl[o] = ll;
  }
}

// concat gate_b/up_b interleaved -> [8][6912]
__global__ __launch_bounds__(256) void concat_bias_kernel(
    const float* __restrict__ gb, const float* __restrict__ ub, float* __restrict__ out)
{
  int idx = blockIdx.x * 256 + threadIdx.x;
  if (idx >= 8 * 6912) return;
  int l = idx / 6912, j = idx - l * 6912;
  out[idx] = (j & 1) ? ub[l * 3456 + (j >> 1)] : gb[l * 3456 + (j >> 1)];
}

// =======================================================================
// MFMA flash attention. block = (q-tile 64, head), 4 waves, KVBLK=32.
// =======================================================================
template<bool FULL>
__global__ __launch_bounds__(256) void attn_mfma(
    const unsigned short* __restrict__ Qh, const unsigned short* __restrict__ Ql,
    const unsigned short* __restrict__ Kh, const unsigned short* __restrict__ Kl,
    const unsigned short* __restrict__ Vth, const unsigned short* __restrict__ Vtl,
    unsigned short* __restrict__ Oh, unsigned short* __restrict__ Ol)
{
  __shared__ unsigned short KT[2][2][32 * 128];
  __shared__ unsigned short VS[2][2][80 * 32];
  __shared__ unsigned short PS[2][64 * 40];
  const int tid = threadIdx.x, lane = tid & 63, wv = tid >> 6;
  const int qb = blockIdx.x, h = blockIdx.y;
  const int fr = lane & 15, kg = lane >> 4;

  short8 qfh[3], qfl[3];
  {
    size_t qbase = ((size_t)h * 1024 + qb * 64 + wv * 16 + fr) * 128;
    #pragma unroll
    for (int ks = 0; ks < 3; ks++){
      qfh[ks] = *(const short8*)(Qh + qbase + ks * 32 + kg * 8);
      qfl[ks] = *(const short8*)(Ql + qbase + ks * 32 + kg * 8);
    }
  }
  float m_r[4], l_r[4];
  #pragma unroll
  for (int r = 0; r < 4; r++){ m_r[r] = -3e38f; l_r[r] = 0.f; }
  floatx4 oa[5];
  #pragma unroll
  for (int nb = 0; nb < 5; nb++) oa[nb] = 0.f;

  const int nt  = FULL ? 32 : 2;
  const int kt0 = FULL ? 0 : qb * 2;

  auto stageK = [&](int buf, int kt){
    #pragma unroll
    for (int p = 0; p < 2; p++){
      int lin = p * 256 + tid;
      int row = lin >> 4, gg = (lin & 15) ^ (row & 7);
      size_t go = ((size_t)h * 1024 + kt * 32 + row) * 128 + gg * 8;
      gld_lds16(Kh + go, &KT[buf][0][(p * 256 + wv * 64) * 8]);
      gld_lds16(Kl + go, &KT[buf][1][(p * 256 + wv * 64) * 8]);
    }
    #pragma unroll
    for (int p = 0; p < 2; p++){
      int lin = p * 256 + tid;
      if (lin < 320){
        int row = lin >> 2, gg = (lin & 3) ^ (row & 3);
        size_t go = ((size_t)h * 80 + row) * 1024 + kt * 32 + gg * 8;
        gld_lds16(Vth + go, &VS[buf][0][(p * 256 + wv * 64) * 8]);
        gld_lds16(Vtl + go, &VS[buf][1][(p * 256 + wv * 64) * 8]);
      }
    }
  };

  stageK(0, kt0);
  __syncthreads();
  for (int t = 0; t < nt; t++){
    const int buf = t & 1;
    if (t + 1 < nt) stageK(buf ^ 1, kt0 + t + 1);
    floatx4 accS[2];
    accS[0] = 0.f; accS[1] = 0.f;
    #pragma unroll
    for (int c = 0; c < 2; c++){
      #pragma unroll
      for (int ks = 0; ks < 3; ks++){
        int row = c * 16 + fr;
        int off = row * 256 + ((ks * 64 + kg * 16) ^ ((row & 7) << 4));
        short8 kh_ = *(const short8*)((const char*)&KT[buf][0][0] + off);
        short8 kl_ = *(const short8*)((const char*)&KT[buf][1][0] + off);
        accS[c] = mfma(qfl[ks], kh_, accS[c]);
        accS[c] = mfma(qfh[ks], kl_, accS[c]);
        accS[c] = mfma(qfh[ks], kh_, accS[c]);
      }
    }
    float corr[4], ps_[4];
    #pragma unroll
    for (int r = 0; r < 4; r++){
      float v = fmaxf(accS[0][r], accS[1][r]);
      v = fmaxf(v, __shfl_xor(v, 1)); v = fmaxf(v, __shfl_xor(v, 2));
      v = fmaxf(v, __shfl_xor(v, 4)); v = fmaxf(v, __shfl_xor(v, 8));
      float mn = fmaxf(m_r[r], v);
      corr[r] = __expf(m_r[r] - mn);
      m_r[r] = mn;
      ps_[r] = 0.f;
    }
    #pragma unroll
    for (int c = 0; c < 2; c++)
      #pragma unroll
      for (int r = 0; r < 4; r++){
        float p = __expf(accS[c][r] - m_r[r]);
        ps_[r] += p;
        unsigned short ph, pl; split_bf(p, ph, pl);
        int po = (wv * 16 + kg * 4 + r) * 40 + c * 16 + fr;
        PS[0][po] = ph;
        PS[1][po] = pl;
      }
    #pragma unroll
    for (int r = 0; r < 4; r++){
      float v = ps_[r];
      v += __shfl_xor(v, 1); v += __shfl_xor(v, 2);
      v += __shfl_xor(v, 4); v += __shfl_xor(v, 8);
      l_r[r] = l_r[r] * corr[r] + v;
      #pragma unroll
      for (int nb = 0; nb < 5; nb++) oa[nb][r] *= corr[r];
    }
    {
      int poff = (wv * 16 + fr) * 80 + kg * 16;
      short8 pah = *(const short8*)((const char*)&PS[0][0] + poff);
      short8 pal = *(const short8*)((const char*)&PS[1][0] + poff);
      #pragma unroll
      for (int nb = 0; nb < 5; nb++){
        int row = nb * 16 + fr;
        int off = row * 64 + ((kg * 16) ^ ((row & 3) << 4));
        short8 vh_ = *(const short8*)((const char*)&VS[buf][0][0] + off);
        short8 vl_ = *(const short8*)((const char*)&VS[buf][1][0] + off);
        oa[nb] = mfma(pal, vh_, oa[nb]);
        oa[nb] = mfma(pah, vl_, oa[nb]);
        oa[nb] = mfma(pah, vh_, oa[nb]);
      }
    }
    __syncthreads();
  }
  float linv[4];
  #pragma unroll
  for (int r = 0; r < 4; r++) linv[r] = 1.f / l_r[r];
  #pragma unroll
  for (int nb = 0; nb < 5; nb++)
    #pragma unroll
    for (int r = 0; r < 4; r++){
      float v = oa[nb][r] * linv[r];
      unsigned short hh, ll; split_bf(v, hh, ll);
      size_t o = (size_t)(qb * 64 + wv * 16 + kg * 4 + r) * 1280 + h * 80 + nb * 16 + fr;
      Oh[o] = hh; Ol[o] = ll;
    }
}

// =======================================================================
extern "C" void kernel_launch(void* const* d_in, const int* in_sizes, int n_in,
                              void* d_out, int out_size, void* d_ws, size_t ws_size,
                              hipStream_t stream)
{
  (void)in_sizes; (void)n_in; (void)out_size;
  const float* images  = (const float*)d_in[0];
  const int*   win     = (const int*)  d_in[1];
  const float* rpe     = (const float*)d_in[3];
  const float* patch_w = (const float*)d_in[6];
  const float* ln1_w   = (const float*)d_in[7];
  const float* ln2_w   = (const float*)d_in[8];
  const float* qkv_w   = (const float*)d_in[9];
  const float* qkv_b   = (const float*)d_in[10];
  const float* proj_w  = (const float*)d_in[11];
  const float* proj_b  = (const float*)d_in[12];
  const float* gate_w  = (const float*)d_in[13];
  const float* up_w    = (const float*)d_in[15];
  const float* down_w  = (const float*)d_in[17];
  const float* down_b  = (const float*)d_in[18];
  const float* lnq_w   = (const float*)d_in[19];
  const float* m1_w    = (const float*)d_in[20];
  const float* m1_b    = (const float*)d_in[21];
  const float* m2_w    = (const float*)d_in[22];
  const float* m2_b    = (const float*)d_in[23];
  const float* gate_b  = (const float*)d_in[14];
  const float* up_b    = (const float*)d_in[16];

  char* ws = (char*)d_ws;
  size_t off = 0;
  auto alloc = [&](size_t b){ size_t o = off; off += (b + 255) & ~(size_t)255; return o; };
  unsigned short* WPH = (unsigned short*)(ws + alloc(26214400ull * 2));  // 52.4MB
  unsigned short* WPL = (unsigned short*)(ws + alloc(26214400ull * 2));
  float* PART = (float*)(ws + alloc(2ull * 1024 * 3840 * 4));            // 31.5MB
  unsigned short* Xh  = (unsigned short*)(ws + alloc(1024ull * 1216 * 2));
  unsigned short* Xl  = (unsigned short*)(ws + alloc(1024ull * 1216 * 2));
  unsigned short* ANh = (unsigned short*)(ws + alloc(1024ull * 1280 * 2));
  unsigned short* ANl = (unsigned short*)(ws + alloc(1024ull * 1280 * 2));
  float* H    = (float*)(ws + alloc(1024ull * 1280 * 4));
  float* QKV  = (float*)(ws + alloc(1024ull * 3840 * 4));
  unsigned short* Qph = (unsigned short*)(ws + alloc(16ull * 1024 * 128 * 2));
  unsigned short* Qpl = (unsigned short*)(ws + alloc(16ull * 1024 * 128 * 2));
  unsigned short* Kph = (unsigned short*)(ws + alloc(16ull * 1024 * 128 * 2));
  unsigned short* Kpl = (unsigned short*)(ws + alloc(16ull * 1024 * 128 * 2));
  unsigned short* Vth = (unsigned short*)(ws + alloc(16ull * 80 * 1024 * 2));
  unsigned short* Vtl = (unsigned short*)(ws + alloc(16ull * 80 * 1024 * 2));
  unsigned short* Ohh = (unsigned short*)(ws + alloc(1024ull * 1280 * 2));
  unsigned short* Oll = (unsigned short*)(ws + alloc(1024ull * 1280 * 2));
  unsigned short* DAh = (unsigned short*)(ws + alloc(1024ull * 3456 * 2));
  unsigned short* DAl = (unsigned short*)(ws + alloc(1024ull * 3456 * 2));
  unsigned short* G1h = (unsigned short*)(ws + alloc(256ull * 5120 * 2));
  unsigned short* G1l = (unsigned short*)(ws + alloc(256ull * 5120 * 2));
  float* COSb = (float*)(ws + alloc(1024ull * 80 * 4));
  float* SINb = (float*)(ws + alloc(1024ull * 80 * 4));
  float* BGU  = (float*)(ws + alloc(8ull * 6912 * 4));
  if (off > ws_size) return;

  gather_x_kernel   <<<4864, 256, 0, stream>>>(images, win, Xh, Xl);
  rope_tables_kernel<<<320,  256, 0, stream>>>(rpe, win, COSb, SINb);
  concat_bias_kernel<<<216,  256, 0, stream>>>(gate_b, up_b, BGU);

  // patch embed: split-K2
  convert_w_kernel<<<dim3(19, 20), 256, 0, stream>>>(patch_w, WPH, WPL, 1176, 1280, 0, 1216, 0, 1, 0);
  gemm_bf2<64, 64, 0, 2><<<dim3(20, 16, 2), 256, 0, stream>>>(
      Xh, Xl, WPH, WPL, nullptr, nullptr, nullptr, nullptr, 1216, 1280, 1024, PART);
  reduce_k<0><<<1280, 256, 0, stream>>>(PART, 2, 1024, 1280, nullptr, nullptr,
      H, nullptr, nullptr, nullptr);

  for (int i = 0; i < 8; i++){
    rmsnorm_kernel<<<1024, 256, 0, stream>>>(H, ln1_w + (size_t)i * 1280, ANh, ANl);
    // qkv: split-K2
    convert_w_kernel<<<dim3(20, 60), 256, 0, stream>>>(
        qkv_w + (size_t)i * 1280 * 3840, WPH, WPL, 1280, 3840, 0, 1280, 0, 1, 0);
    gemm_bf2<64, 128, 0, 2><<<dim3(30, 16, 2), 256, 0, stream>>>(
        ANh, ANl, WPH, WPL, nullptr, nullptr, nullptr, nullptr, 1280, 3840, 1024, PART);
    reduce_k<0><<<3840, 256, 0, stream>>>(PART, 2, 1024, 3840,
        qkv_b + (size_t)i * 3840, nullptr, QKV, nullptr, nullptr, nullptr);
    rope_qk_kernel<<<8192, 256, 0, stream>>>(QKV, COSb, SINb, Qph, Qpl, Kph, Kpl);
    vt_kernel<<<dim3(16, 16), 256, 0, stream>>>(QKV, Vth, Vtl);
    if (i == 3 || i == 7)
      attn_mfma<true ><<<dim3(16, 16), 256, 0, stream>>>(Qph, Qpl, Kph, Kpl, Vth, Vtl, Ohh, Oll);
    else
      attn_mfma<false><<<dim3(16, 16), 256, 0, stream>>>(Qph, Qpl, Kph, Kpl, Vth, Vtl, Ohh, Oll);
    // proj: split-K2 + residual in reduce
    convert_w_kernel<<<dim3(20, 20), 256, 0, stream>>>(
        proj_w + (size_t)i * 1280 * 1280, WPH, WPL, 1280, 1280, 0, 1280, 0, 1, 0);
    gemm_bf2<64, 64, 0, 2><<<dim3(20, 16, 2), 256, 0, stream>>>(
        Ohh, Oll, WPH, WPL, nullptr, nullptr, nullptr, nullptr, 1280, 1280, 1024, PART);
    reduce_k<1><<<1280, 256, 0, stream>>>(PART, 2, 1024, 1280,
        proj_b + (size_t)i * 1280, H, H, nullptr, nullptr, nullptr);
    rmsnorm_kernel<<<1024, 256, 0, stream>>>(H, ln2_w + (size_t)i * 1280, ANh, ANl);
    // fused gate+up (interleaved) direct MODE 4
    convert_w_kernel<<<dim3(20, 54), 256, 0, stream>>>(
        gate_w + (size_t)i * 1280 * 3456, WPH, WPL, 1280, 3456, 0, 1280, 0, 2, 0);
    convert_w_kernel<<<dim3(20, 54), 256, 0, stream>>>(
        up_w + (size_t)i * 1280 * 3456, WPH, WPL, 1280, 3456, 0, 1280, 0, 2, 1);
    gemm_bf2<64, 128, 4, 1><<<dim3(54, 16), 256, 0, stream>>>(
        ANh, ANl, WPH, WPL, BGU + (size_t)i * 6912, nullptr, DAh, DAl,
        1280, 6912, 1024, nullptr);
    // down: split-K2 + residual in reduce
    convert_w_kernel<<<dim3(54, 20), 256, 0, stream>>>(
        down_w + (size_t)i * 3456 * 1280, WPH, WPL, 3456, 1280, 0, 3456, 0, 1, 0);
    gemm_bf2<64, 64, 0, 2><<<dim3(20, 16, 2), 256, 0, stream>>>(
        DAh, DAl, WPH, WPL, nullptr, nullptr, nullptr, nullptr, 3456, 1280, 1024, PART);
    reduce_k<1><<<1280, 256, 0, stream>>>(PART, 2, 1024, 1280,
        down_b + (size_t)i * 1280, H, H, nullptr, nullptr, nullptr);
  }

  // merger
  rmsnorm_kernel<<<1024, 256, 0, stream>>>(H, lnq_w, ANh, ANl);
  // m1: 256x5120x5120, split-K4, gelu -> planes
  convert_w_kernel<<<dim3(80, 80), 256, 0, stream>>>(m1_w, WPH, WPL, 5120, 5120, 0, 5120, 0, 1, 0);
  gemm_bf2<64, 64, 0, 4><<<dim3(80, 4, 4), 256, 0, stream>>>(
      ANh, ANl, WPH, WPL, nullptr, nullptr, nullptr, nullptr, 5120, 5120, 256, PART);
  reduce_k<2><<<1280, 256, 0, stream>>>(PART, 4, 256, 5120,
      m1_b, nullptr, nullptr, G1h, G1l, nullptr);
  // m2: 256x3584x5120, split-K4, scatter rows
  convert_w_kernel<<<dim3(80, 56), 256, 0, stream>>>(m2_w, WPH, WPL, 5120, 3584, 0, 5120, 0, 1, 0);
  gemm_bf2<64, 64, 0, 4><<<dim3(56, 4, 4), 256, 0, stream>>>(
      G1h, G1l, WPH, WPL, nullptr, nullptr, nullptr, nullptr, 5120, 3584, 256, PART);
  reduce_k<3><<<896, 256, 0, stream>>>(PART, 4, 256, 3584,
      m2_b, nullptr, (float*)d_out, nullptr, nullptr, win);
}

// Round 5
// 2525.805 us; speedup vs baseline: 3.2662x; 1.1421x over previous
//
#include <hip/hip_runtime.h>
#include <math.h>

typedef float  floatx4  __attribute__((ext_vector_type(4)));
typedef short  short8   __attribute__((ext_vector_type(8)));
typedef unsigned short ushortx4 __attribute__((ext_vector_type(4)));
typedef unsigned short ushortx8 __attribute__((ext_vector_type(8)));

// ---------- bf16 helpers (RNE) ----------
__device__ inline unsigned short f2bf(float x){
  unsigned u = __float_as_uint(x);
  u += 0x7FFFu + ((u >> 16) & 1u);
  return (unsigned short)(u >> 16);
}
__device__ inline float bf2f(unsigned short b){ return __uint_as_float(((unsigned)b) << 16); }
__device__ inline void split_bf(float x, unsigned short& h, unsigned short& l){
  h = f2bf(x); l = f2bf(x - bf2f(h));
}

// ---------- MFMA 16x16x32 bf16 ----------
// A-frag: lane l holds A[l&15][(l>>4)*8+j]; B-frag: lane l holds B[(l>>4)*8+j][l&15]
// C/D: lane l reg r = D[(l>>4)*4+r][l&15]   (verified rounds 1-4)
__device__ inline floatx4 mfma(short8 a, short8 b, floatx4 c){
  return __builtin_amdgcn_mfma_f32_16x16x32_bf16(a, b, c, 0, 0, 0);
}

// ---------- async global->LDS, 16B per lane ----------
__device__ inline void gld_lds16(const void* g, void* l){
  __builtin_amdgcn_global_load_lds(
      (const __attribute__((address_space(1))) unsigned int*)g,
      (__attribute__((address_space(3))) unsigned int*)l, 16, 0, 0);
}

// =======================================================================
// Dual-plane bf16 GEMM: out[M,N] = (Ah+Al)[M,K] @ (Wh+Wl)^T[N,K]
// Double-buffered LDS, global_load_lds staging, XOR-swizzled granules,
// XCD-chunked block swizzle (same-W-panel blocks share an XCD's L2).
// Grids are sized tail-free (total blocks <= LDS-capacity * 256).
// KSPLIT>1: partials to part[(z*Mtot+row)*N + col]; epilogue in reduce_k.
// KSPLIT==1 modes: 0: outf = acc + bias; 4: interleaved gate/up silu.
// =======================================================================
template<int BM, int BN, int MODE, int KSPLIT>
__global__ __launch_bounds__(256) void gemm_bf2(
    const unsigned short* __restrict__ Ah, const unsigned short* __restrict__ Al,
    const unsigned short* __restrict__ Wh, const unsigned short* __restrict__ Wl,
    const float* __restrict__ bias,
    float* __restrict__ outf, unsigned short* __restrict__ outh,
    unsigned short* __restrict__ outl,
    int K, int Nout, int Mtot, float* __restrict__ part)
{
  __shared__ unsigned short SA[2][2][BM*32];
  __shared__ unsigned short SW[2][2][BN*32];
  const int tid = threadIdx.x, lane = tid & 63, wv = tid >> 6;
  const int wm = wv >> 1, wn = wv & 1;

  // ---- XCD-chunked bijective swizzle (id%8 = XCD; m-fastest per chunk)
  int m_idx, n_idx;
  {
    const int gx = gridDim.x, gy = gridDim.y;
    const int T = gx * gy;
    int id = blockIdx.y * gx + blockIdx.x;
    if ((T & 7) == 0){
      int wg = (id & 7) * (T >> 3) + (id >> 3);
      n_idx = wg / gy; m_idx = wg - n_idx * gy;
    } else { n_idx = blockIdx.x; m_idx = blockIdx.y; }
  }
  const int m0 = m_idx * BM, n0 = n_idx * BN;
  const int kbase = (KSPLIT > 1) ? blockIdx.z * (K / KSPLIT) : 0;
  constexpr int MR = BM / 32, NR = BN / 32;
  floatx4 acc[MR][NR];
  #pragma unroll
  for (int mr = 0; mr < MR; mr++)
    #pragma unroll
    for (int nr = 0; nr < NR; nr++) acc[mr][nr] = 0.f;
  const int fr = lane & 15, kg = lane >> 4;

  auto stage = [&](int buf, int k0){
    #pragma unroll
    for (int p = 0; p < (BM * 4) / 256; p++){
      int lin = p * 256 + tid;
      int row = lin >> 2, gg = (lin & 3) ^ ((row >> 1) & 3);
      size_t go = (size_t)(m0 + row) * K + kbase + k0 + gg * 8;
      gld_lds16(Ah + go, &SA[buf][0][(p * 256 + wv * 64) * 8]);
      gld_lds16(Al + go, &SA[buf][1][(p * 256 + wv * 64) * 8]);
    }
    #pragma unroll
    for (int p = 0; p < (BN * 4) / 256; p++){
      int lin = p * 256 + tid;
      int row = lin >> 2, gg = (lin & 3) ^ ((row >> 1) & 3);
      size_t go = (size_t)(n0 + row) * K + kbase + k0 + gg * 8;
      gld_lds16(Wh + go, &SW[buf][0][(p * 256 + wv * 64) * 8]);
      gld_lds16(Wl + go, &SW[buf][1][(p * 256 + wv * 64) * 8]);
    }
  };

  stage(0, 0);
  __syncthreads();
  const int nt = (K / KSPLIT) >> 5;
  for (int t = 0; t < nt; t++){
    const int buf = t & 1;
    if (t + 1 < nt) stage(buf ^ 1, (t + 1) << 5);
    short8 ah[MR], al[MR], wh[NR], wl[NR];
    #pragma unroll
    for (int mr = 0; mr < MR; mr++){
      int r = wm * (BM / 2) + mr * 16 + fr;
      int off = r * 64 + ((kg ^ ((r >> 1) & 3)) << 4);
      ah[mr] = *(const short8*)((const char*)&SA[buf][0][0] + off);
      al[mr] = *(const short8*)((const char*)&SA[buf][1][0] + off);
    }
    #pragma unroll
    for (int nr = 0; nr < NR; nr++){
      int r = wn * (BN / 2) + nr * 16 + fr;
      int off = r * 64 + ((kg ^ ((r >> 1) & 3)) << 4);
      wh[nr] = *(const short8*)((const char*)&SW[buf][0][0] + off);
      wl[nr] = *(const short8*)((const char*)&SW[buf][1][0] + off);
    }
    #pragma unroll
    for (int mr = 0; mr < MR; mr++)
      #pragma unroll
      for (int nr = 0; nr < NR; nr++){
        acc[mr][nr] = mfma(al[mr], wh[nr], acc[mr][nr]);
        acc[mr][nr] = mfma(ah[mr], wl[nr], acc[mr][nr]);
        acc[mr][nr] = mfma(ah[mr], wh[nr], acc[mr][nr]);
      }
    __syncthreads();
  }
  #pragma unroll
  for (int mr = 0; mr < MR; mr++)
    #pragma unroll
    for (int nr = 0; nr < NR; nr++){
      int np = n0 + wn * (BN / 2) + nr * 16 + fr;
      #pragma unroll
      for (int e = 0; e < 4; e++){
        int row = m0 + wm * (BM / 2) + mr * 16 + kg * 4 + e;
        float v = acc[mr][nr][e];
        if (KSPLIT > 1){
          part[((size_t)blockIdx.z * Mtot + row) * Nout + np] = v;
        } else {
          v += bias ? bias[np] : 0.f;
          if (MODE == 0) outf[(size_t)row * Nout + np] = v;
          if (MODE == 4){
            float pv = __shfl_xor(v, 1);
            if (!(fr & 1)){
              float dv = v / (1.f + __expf(-v)) * pv;
              unsigned short hh, ll; split_bf(dv, hh, ll);
              outh[(size_t)row * (Nout >> 1) + (np >> 1)] = hh;
              outl[(size_t)row * (Nout >> 1) + (np >> 1)] = ll;
            }
          }
        }
      }
    }
}

// =======================================================================
// Split-K reduce + epilogue. part[z][M][N] f32, fixed-order sum.
// MODE 0: outf = sum + bias
// MODE 1: outf = sum + bias + res (res may alias outf)
// MODE 2: planes = gelu_exact(sum + bias)
// MODE 3: outf[rowmap[row]*N + col] = sum + bias
// =======================================================================
template<int MODE>
__global__ __launch_bounds__(256) void reduce_k(
    const float* __restrict__ part, int Z, int M, int N,
    const float* __restrict__ bias, const float* __restrict__ res,
    float* __restrict__ outf, unsigned short* __restrict__ outh,
    unsigned short* __restrict__ outl, const int* __restrict__ rowmap)
{
  int idx4 = (blockIdx.x * 256 + threadIdx.x) * 4;
  if (idx4 >= M * N) return;
  int row = idx4 / N, col = idx4 - row * N;
  floatx4 v = *(const floatx4*)(part + (size_t)row * N + col);
  for (int z = 1; z < Z; z++){
    floatx4 p = *(const floatx4*)(part + ((size_t)z * M + row) * N + col);
    v[0] += p[0]; v[1] += p[1]; v[2] += p[2]; v[3] += p[3];
  }
  if (bias){
    floatx4 b = *(const floatx4*)(bias + col);
    v[0] += b[0]; v[1] += b[1]; v[2] += b[2]; v[3] += b[3];
  }
  if (MODE == 1){
    floatx4 r = *(const floatx4*)(res + (size_t)row * N + col);
    v[0] += r[0]; v[1] += r[1]; v[2] += r[2]; v[3] += r[3];
  }
  if (MODE == 0 || MODE == 1){
    *(floatx4*)(outf + (size_t)row * N + col) = v;
  } else if (MODE == 2){
    ushortx4 hh, ll;
    #pragma unroll
    for (int j = 0; j < 4; j++){
      float g = 0.5f * v[j] * (1.f + erff(v[j] * 0.70710678118654752f));
      unsigned short h, l; split_bf(g, h, l);
      hh[j] = h; ll[j] = l;
    }
    *(ushortx4*)(outh + (size_t)row * N + col) = hh;
    *(ushortx4*)(outl + (size_t)row * N + col) = ll;
  } else if (MODE == 3){
    *(floatx4*)(outf + (size_t)rowmap[row] * N + col) = v;
  }
}

// =======================================================================
// Weight convert: W f32 [K][Nstride] (cols at n_src0) -> transposed hi/lo
// planes at row (plane_row0 + n*row_mul + row_add), [.][Kpad], zero-pad k>=K
// =======================================================================
__global__ __launch_bounds__(256) void convert_w_kernel(
    const float* __restrict__ W, unsigned short* __restrict__ PH,
    unsigned short* __restrict__ PL,
    int K, int Nstride, int n_src0, int Kpad, int plane_row0,
    int row_mul, int row_add)
{
  __shared__ float T[64][68];
  const int tid = threadIdx.x;
  const int k0 = blockIdx.x * 64, n0 = blockIdx.y * 64;
  const int kr = tid >> 4, nc = (tid & 15) << 2;
  #pragma unroll
  for (int p = 0; p < 4; p++){
    int k = k0 + p * 16 + kr;
    floatx4 v = {0.f, 0.f, 0.f, 0.f};
    if (k < K) v = *(const floatx4*)(W + (size_t)k * Nstride + n_src0 + n0 + nc);
    *(floatx4*)&T[p * 16 + kr][nc] = v;
  }
  __syncthreads();
  const int n = tid >> 2, kc = (tid & 3) << 4;
  ushortx8 h0, h1, l0, l1;
  #pragma unroll
  for (int j = 0; j < 8; j++){
    unsigned short h, l;
    split_bf(T[kc + j][n], h, l);       h0[j] = h; l0[j] = l;
    split_bf(T[kc + 8 + j][n], h, l);   h1[j] = h; l1[j] = l;
  }
  size_t ro = (size_t)(plane_row0 + (n0 + n) * row_mul + row_add) * Kpad + k0 + kc;
  *(ushortx8*)&PH[ro] = h0; *(ushortx8*)&PH[ro + 8] = h1;
  *(ushortx8*)&PL[ro] = l0; *(ushortx8*)&PL[ro + 8] = l1;
}

// =======================================================================
// RMSNorm: f32 row -> hi/lo bf16 planes. One block per row, D=1280.
// =======================================================================
__global__ __launch_bounds__(256) void rmsnorm_kernel(
    const float* __restrict__ x, const float* __restrict__ w,
    unsigned short* __restrict__ yh, unsigned short* __restrict__ yl)
{
  const int row = blockIdx.x;
  const float* xr = x + (size_t)row * 1280;
  float ss = 0.f;
  for (int i = threadIdx.x; i < 1280; i += 256){ float v = xr[i]; ss = fmaf(v, v, ss); }
  for (int o = 32; o > 0; o >>= 1) ss += __shfl_down(ss, o);
  __shared__ float wsum[4];
  __shared__ float snorm;
  if ((threadIdx.x & 63) == 0) wsum[threadIdx.x >> 6] = ss;
  __syncthreads();
  if (threadIdx.x == 0){
    float t = wsum[0] + wsum[1] + wsum[2] + wsum[3];
    snorm = 1.0f / sqrtf(t * (1.0f / 1280.0f) + 1e-6f);
  }
  __syncthreads();
  float s = snorm;
  for (int i = threadIdx.x; i < 1280; i += 256){
    float v = xr[i] * s * w[i];
    unsigned short h, l; split_bf(v, h, l);
    yh[(size_t)row * 1280 + i] = h;
    yl[(size_t)row * 1280 + i] = l;
  }
}

// =======================================================================
// Patch gather (window perm folded) -> hi/lo planes [1024][1216]
// =======================================================================
__global__ __launch_bounds__(256) void gather_x_kernel(
    const float* __restrict__ img, const int* __restrict__ win,
    unsigned short* __restrict__ Xh, unsigned short* __restrict__ Xl)
{
  int idx = blockIdx.x * 256 + threadIdx.x;
  if (idx >= 1024 * 1216) return;
  int s = idx / 1216, f = idx - s * 1216;
  float val = 0.f;
  if (f < 1176){
    int sp = (win[s >> 2] << 2) | (s & 3);
    int i0 = sp >> 6, r = sp & 63;
    int i3 = r >> 2, rr = r & 3, i1 = rr >> 1, i4 = rr & 1;
    int c  = f / 392, f2 = f - c * 392;
    int f3 = f2 % 196;
    int ph = f3 / 14, pw2 = f3 - ph * 14;
    int hp = (i0 * 2 + i1) * 14 + ph, wp = (i3 * 2 + i4) * 14 + pw2;
    val = img[((size_t)c * 448 + hp) * 448 + wp];
  }
  unsigned short h, l; split_bf(val, h, l);
  Xh[idx] = h; Xl[idx] = l;
}

__global__ __launch_bounds__(256) void rope_tables_kernel(
    const float* __restrict__ rpe, const int* __restrict__ win,
    float* __restrict__ cosb, float* __restrict__ sinb)
{
  int idx = blockIdx.x * 256 + threadIdx.x;
  if (idx >= 1024 * 80) return;
  int s = idx / 80, d = idx - s * 80;
  int src = (win[s >> 2] << 2) | (s & 3);
  float ang = rpe[src * 40 + (d % 40)];
  cosb[idx] = cosf(ang);
  sinb[idx] = sinf(ang);
}

// qkv f32 -> rope'd Q (pre-scaled), K as hi/lo planes [16][1024][128] (d-pad 0)
__global__ __launch_bounds__(256) void rope_qk_kernel(
    const float* __restrict__ qkv, const float* __restrict__ cosb, const float* __restrict__ sinb,
    unsigned short* __restrict__ Qh, unsigned short* __restrict__ Ql,
    unsigned short* __restrict__ Kh, unsigned short* __restrict__ Kl)
{
  int idx = blockIdx.x * 256 + threadIdx.x;
  if (idx >= 1024 * 16 * 128) return;
  int s = idx >> 11;
  int rem = idx & 2047;
  int h = rem >> 7, d = rem & 127;
  size_t o = ((size_t)h * 1024 + s) * 128 + d;
  if (d >= 80){ Qh[o] = 0; Ql[o] = 0; Kh[o] = 0; Kl[o] = 0; return; }
  const float* base = qkv + (size_t)s * 3840;
  float qv = base[h * 80 + d], kv = base[1280 + h * 80 + d];
  float qo = (d < 40) ? -base[h * 80 + d + 40] : base[h * 80 + d - 40];
  float ko = (d < 40) ? -base[1280 + h * 80 + d + 40] : base[1280 + h * 80 + d - 40];
  float cc = cosb[s * 80 + d], sn = sinb[s * 80 + d];
  float q = (qv * cc + qo * sn) * 0.11180339887498949f;
  float k = kv * cc + ko * sn;
  unsigned short hh, ll;
  split_bf(q, hh, ll); Qh[o] = hh; Ql[o] = ll;
  split_bf(k, hh, ll); Kh[o] = hh; Kl[o] = ll;
}

// V transpose: qkv f32 -> VT planes [16][80][1024]
__global__ __launch_bounds__(256) void vt_kernel(
    const float* __restrict__ qkv,
    unsigned short* __restrict__ Vth, unsigned short* __restrict__ Vtl)
{
  __shared__ float T[64][81];
  const int h = blockIdx.y, s0 = blockIdx.x * 64;
  for (int c = threadIdx.x; c < 64 * 80; c += 256){
    int sl = c / 80, d = c - sl * 80;
    T[sl][d] = qkv[(size_t)(s0 + sl) * 3840 + 2560 + h * 80 + d];
  }
  __syncthreads();
  for (int c = threadIdx.x; c < 80 * 64; c += 256){
    int d = c >> 6, sl = c & 63;
    unsigned short hh, ll; split_bf(T[sl][d], hh, ll);
    size_t o = ((size_t)h * 80 + d) * 1024 + s0 + sl;
    Vth[o] = hh; Vtl[o] = ll;
  }
}

// concat gate_b/up_b interleaved -> [8][6912]
__global__ __launch_bounds__(256) void concat_bias_kernel(
    const float* __restrict__ gb, const float* __restrict__ ub, float* __restrict__ out)
{
  int idx = blockIdx.x * 256 + threadIdx.x;
  if (idx >= 8 * 6912) return;
  int l = idx / 6912, j = idx - l * 6912;
  out[idx] = (j & 1) ? ub[l * 3456 + (j >> 1)] : gb[l * 3456 + (j >> 1)];
}

// =======================================================================
// MFMA flash attention. block = (q-tile 64, head), 4 waves, KVBLK=32.
// =======================================================================
template<bool FULL>
__global__ __launch_bounds__(256) void attn_mfma(
    const unsigned short* __restrict__ Qh, const unsigned short* __restrict__ Ql,
    const unsigned short* __restrict__ Kh, const unsigned short* __restrict__ Kl,
    const unsigned short* __restrict__ Vth, const unsigned short* __restrict__ Vtl,
    unsigned short* __restrict__ Oh, unsigned short* __restrict__ Ol)
{
  __shared__ unsigned short KT[2][2][32 * 128];
  __shared__ unsigned short VS[2][2][80 * 32];
  __shared__ unsigned short PS[2][64 * 40];
  const int tid = threadIdx.x, lane = tid & 63, wv = tid >> 6;
  const int qb = blockIdx.x, h = blockIdx.y;
  const int fr = lane & 15, kg = lane >> 4;

  short8 qfh[3], qfl[3];
  {
    size_t qbase = ((size_t)h * 1024 + qb * 64 + wv * 16 + fr) * 128;
    #pragma unroll
    for (int ks = 0; ks < 3; ks++){
      qfh[ks] = *(const short8*)(Qh + qbase + ks * 32 + kg * 8);
      qfl[ks] = *(const short8*)(Ql + qbase + ks * 32 + kg * 8);
    }
  }
  float m_r[4], l_r[4];
  #pragma unroll
  for (int r = 0; r < 4; r++){ m_r[r] = -3e38f; l_r[r] = 0.f; }
  floatx4 oa[5];
  #pragma unroll
  for (int nb = 0; nb < 5; nb++) oa[nb] = 0.f;

  const int nt  = FULL ? 32 : 2;
  const int kt0 = FULL ? 0 : qb * 2;

  auto stageK = [&](int buf, int kt){
    #pragma unroll
    for (int p = 0; p < 2; p++){
      int lin = p * 256 + tid;
      int row = lin >> 4, gg = (lin & 15) ^ (row & 7);
      size_t go = ((size_t)h * 1024 + kt * 32 + row) * 128 + gg * 8;
      gld_lds16(Kh + go, &KT[buf][0][(p * 256 + wv * 64) * 8]);
      gld_lds16(Kl + go, &KT[buf][1][(p * 256 + wv * 64) * 8]);
    }
    #pragma unroll
    for (int p = 0; p < 2; p++){
      int lin = p * 256 + tid;
      if (lin < 320){
        int row = lin >> 2, gg = (lin & 3) ^ (row & 3);
        size_t go = ((size_t)h * 80 + row) * 1024 + kt * 32 + gg * 8;
        gld_lds16(Vth + go, &VS[buf][0][(p * 256 + wv * 64) * 8]);
        gld_lds16(Vtl + go, &VS[buf][1][(p * 256 + wv * 64) * 8]);
      }
    }
  };

  stageK(0, kt0);
  __syncthreads();
  for (int t = 0; t < nt; t++){
    const int buf = t & 1;
    if (t + 1 < nt) stageK(buf ^ 1, kt0 + t + 1);
    floatx4 accS[2];
    accS[0] = 0.f; accS[1] = 0.f;
    #pragma unroll
    for (int c = 0; c < 2; c++){
      #pragma unroll
      for (int ks = 0; ks < 3; ks++){
        int row = c * 16 + fr;
        int off = row * 256 + ((ks * 64 + kg * 16) ^ ((row & 7) << 4));
        short8 kh_ = *(const short8*)((const char*)&KT[buf][0][0] + off);
        short8 kl_ = *(const short8*)((const char*)&KT[buf][1][0] + off);
        accS[c] = mfma(qfl[ks], kh_, accS[c]);
        accS[c] = mfma(qfh[ks], kl_, accS[c]);
        accS[c] = mfma(qfh[ks], kh_, accS[c]);
      }
    }
    float corr[4], ps_[4];
    #pragma unroll
    for (int r = 0; r < 4; r++){
      float v = fmaxf(accS[0][r], accS[1][r]);
      v = fmaxf(v, __shfl_xor(v, 1)); v = fmaxf(v, __shfl_xor(v, 2));
      v = fmaxf(v, __shfl_xor(v, 4)); v = fmaxf(v, __shfl_xor(v, 8));
      float mn = fmaxf(m_r[r], v);
      corr[r] = __expf(m_r[r] - mn);
      m_r[r] = mn;
      ps_[r] = 0.f;
    }
    #pragma unroll
    for (int c = 0; c < 2; c++)
      #pragma unroll
      for (int r = 0; r < 4; r++){
        float p = __expf(accS[c][r] - m_r[r]);
        ps_[r] += p;
        unsigned short ph, pl; split_bf(p, ph, pl);
        int po = (wv * 16 + kg * 4 + r) * 40 + c * 16 + fr;
        PS[0][po] = ph;
        PS[1][po] = pl;
      }
    #pragma unroll
    for (int r = 0; r < 4; r++){
      float v = ps_[r];
      v += __shfl_xor(v, 1); v += __shfl_xor(v, 2);
      v += __shfl_xor(v, 4); v += __shfl_xor(v, 8);
      l_r[r] = l_r[r] * corr[r] + v;
      #pragma unroll
      for (int nb = 0; nb < 5; nb++) oa[nb][r] *= corr[r];
    }
    {
      int poff = (wv * 16 + fr) * 80 + kg * 16;
      short8 pah = *(const short8*)((const char*)&PS[0][0] + poff);
      short8 pal = *(const short8*)((const char*)&PS[1][0] + poff);
      #pragma unroll
      for (int nb = 0; nb < 5; nb++){
        int row = nb * 16 + fr;
        int off = row * 64 + ((kg * 16) ^ ((row & 3) << 4));
        short8 vh_ = *(const short8*)((const char*)&VS[buf][0][0] + off);
        short8 vl_ = *(const short8*)((const char*)&VS[buf][1][0] + off);
        oa[nb] = mfma(pal, vh_, oa[nb]);
        oa[nb] = mfma(pah, vl_, oa[nb]);
        oa[nb] = mfma(pah, vh_, oa[nb]);
      }
    }
    __syncthreads();
  }
  float linv[4];
  #pragma unroll
  for (int r = 0; r < 4; r++) linv[r] = 1.f / l_r[r];
  #pragma unroll
  for (int nb = 0; nb < 5; nb++)
    #pragma unroll
    for (int r = 0; r < 4; r++){
      float v = oa[nb][r] * linv[r];
      unsigned short hh, ll; split_bf(v, hh, ll);
      size_t o = (size_t)(qb * 64 + wv * 16 + kg * 4 + r) * 1280 + h * 80 + nb * 16 + fr;
      Oh[o] = hh; Ol[o] = ll;
    }
}

// =======================================================================
extern "C" void kernel_launch(void* const* d_in, const int* in_sizes, int n_in,
                              void* d_out, int out_size, void* d_ws, size_t ws_size,
                              hipStream_t stream)
{
  (void)in_sizes; (void)n_in; (void)out_size;
  const float* images  = (const float*)d_in[0];
  const int*   win     = (const int*)  d_in[1];
  const float* rpe     = (const float*)d_in[3];
  const float* patch_w = (const float*)d_in[6];
  const float* ln1_w   = (const float*)d_in[7];
  const float* ln2_w   = (const float*)d_in[8];
  const float* qkv_w   = (const float*)d_in[9];
  const float* qkv_b   = (const float*)d_in[10];
  const float* proj_w  = (const float*)d_in[11];
  const float* proj_b  = (const float*)d_in[12];
  const float* gate_w  = (const float*)d_in[13];
  const float* gate_b  = (const float*)d_in[14];
  const float* up_w    = (const float*)d_in[15];
  const float* up_b    = (const float*)d_in[16];
  const float* down_w  = (const float*)d_in[17];
  const float* down_b  = (const float*)d_in[18];
  const float* lnq_w   = (const float*)d_in[19];
  const float* m1_w    = (const float*)d_in[20];
  const float* m1_b    = (const float*)d_in[21];
  const float* m2_w    = (const float*)d_in[22];
  const float* m2_b    = (const float*)d_in[23];

  char* ws = (char*)d_ws;
  size_t off = 0;
  auto alloc = [&](size_t b){ size_t o = off; off += (b + 255) & ~(size_t)255; return o; };
  unsigned short* WPH = (unsigned short*)(ws + alloc(26214400ull * 2));  // 52.4MB
  unsigned short* WPL = (unsigned short*)(ws + alloc(26214400ull * 2));
  float* PART = (float*)(ws + alloc(4ull * 256 * 5120 * 4 + 2ull * 1024 * 1280 * 4));
  unsigned short* Xh  = (unsigned short*)(ws + alloc(1024ull * 1216 * 2));
  unsigned short* Xl  = (unsigned short*)(ws + alloc(1024ull * 1216 * 2));
  unsigned short* ANh = (unsigned short*)(ws + alloc(1024ull * 1280 * 2));
  unsigned short* ANl = (unsigned short*)(ws + alloc(1024ull * 1280 * 2));
  float* H    = (float*)(ws + alloc(1024ull * 1280 * 4));
  float* QKV  = (float*)(ws + alloc(1024ull * 3840 * 4));
  unsigned short* Qph = (unsigned short*)(ws + alloc(16ull * 1024 * 128 * 2));
  unsigned short* Qpl = (unsigned short*)(ws + alloc(16ull * 1024 * 128 * 2));
  unsigned short* Kph = (unsigned short*)(ws + alloc(16ull * 1024 * 128 * 2));
  unsigned short* Kpl = (unsigned short*)(ws + alloc(16ull * 1024 * 128 * 2));
  unsigned short* Vth = (unsigned short*)(ws + alloc(16ull * 80 * 1024 * 2));
  unsigned short* Vtl = (unsigned short*)(ws + alloc(16ull * 80 * 1024 * 2));
  unsigned short* Ohh = (unsigned short*)(ws + alloc(1024ull * 1280 * 2));
  unsigned short* Oll = (unsigned short*)(ws + alloc(1024ull * 1280 * 2));
  unsigned short* DAh = (unsigned short*)(ws + alloc(1024ull * 3456 * 2));
  unsigned short* DAl = (unsigned short*)(ws + alloc(1024ull * 3456 * 2));
  unsigned short* G1h = (unsigned short*)(ws + alloc(256ull * 5120 * 2));
  unsigned short* G1l = (unsigned short*)(ws + alloc(256ull * 5120 * 2));
  float* COSb = (float*)(ws + alloc(1024ull * 80 * 4));
  float* SINb = (float*)(ws + alloc(1024ull * 80 * 4));
  float* BGU  = (float*)(ws + alloc(8ull * 6912 * 4));
  if (off > ws_size) return;

  gather_x_kernel   <<<4864, 256, 0, stream>>>(images, win, Xh, Xl);
  rope_tables_kernel<<<320,  256, 0, stream>>>(rpe, win, COSb, SINb);
  concat_bias_kernel<<<216,  256, 0, stream>>>(gate_b, up_b, BGU);

  // patch embed: 64x128 split-K2 (320 blocks, tail-free)
  convert_w_kernel<<<dim3(19, 20), 256, 0, stream>>>(patch_w, WPH, WPL, 1176, 1280, 0, 1216, 0, 1, 0);
  gemm_bf2<64, 128, 0, 2><<<dim3(10, 16, 2), 256, 0, stream>>>(
      Xh, Xl, WPH, WPL, nullptr, nullptr, nullptr, nullptr, 1216, 1280, 1024, PART);
  reduce_k<0><<<1280, 256, 0, stream>>>(PART, 2, 1024, 1280, nullptr, nullptr,
      H, nullptr, nullptr, nullptr);

  for (int i = 0; i < 8; i++){
    rmsnorm_kernel<<<1024, 256, 0, stream>>>(H, ln1_w + (size_t)i * 1280, ANh, ANl);
    // qkv: 64x128, no split-K (480 blocks, all resident), bias fused
    convert_w_kernel<<<dim3(20, 60), 256, 0, stream>>>(
        qkv_w + (size_t)i * 1280 * 3840, WPH, WPL, 1280, 3840, 0, 1280, 0, 1, 0);
    gemm_bf2<64, 128, 0, 1><<<dim3(30, 16), 256, 0, stream>>>(
        ANh, ANl, WPH, WPL, qkv_b + (size_t)i * 3840, QKV, nullptr, nullptr,
        1280, 3840, 1024, nullptr);
    rope_qk_kernel<<<8192, 256, 0, stream>>>(QKV, COSb, SINb, Qph, Qpl, Kph, Kpl);
    vt_kernel<<<dim3(16, 16), 256, 0, stream>>>(QKV, Vth, Vtl);
    if (i == 3 || i == 7)
      attn_mfma<true ><<<dim3(16, 16), 256, 0, stream>>>(Qph, Qpl, Kph, Kpl, Vth, Vtl, Ohh, Oll);
    else
      attn_mfma<false><<<dim3(16, 16), 256, 0, stream>>>(Qph, Qpl, Kph, Kpl, Vth, Vtl, Ohh, Oll);
    // proj: 64x128 split-K2 (320 blocks) + residual in reduce
    convert_w_kernel<<<dim3(20, 20), 256, 0, stream>>>(
        proj_w + (size_t)i * 1280 * 1280, WPH, WPL, 1280, 1280, 0, 1280, 0, 1, 0);
    gemm_bf2<64, 128, 0, 2><<<dim3(10, 16, 2), 256, 0, stream>>>(
        Ohh, Oll, WPH, WPL, nullptr, nullptr, nullptr, nullptr, 1280, 1280, 1024, PART);
    reduce_k<1><<<1280, 256, 0, stream>>>(PART, 2, 1024, 1280,
        proj_b + (size_t)i * 1280, H, H, nullptr, nullptr, nullptr);
    rmsnorm_kernel<<<1024, 256, 0, stream>>>(H, ln2_w + (size_t)i * 1280, ANh, ANl);
    // fused gate+up (interleaved): 128x128 (432 blocks, all resident)
    convert_w_kernel<<<dim3(20, 54), 256, 0, stream>>>(
        gate_w + (size_t)i * 1280 * 3456, WPH, WPL, 1280, 3456, 0, 1280, 0, 2, 0);
    convert_w_kernel<<<dim3(20, 54), 256, 0, stream>>>(
        up_w + (size_t)i * 1280 * 3456, WPH, WPL, 1280, 3456, 0, 1280, 0, 2, 1);
    gemm_bf2<128, 128, 4, 1><<<dim3(54, 8), 256, 0, stream>>>(
        ANh, ANl, WPH, WPL, BGU + (size_t)i * 6912, nullptr, DAh, DAl,
        1280, 6912, 1024, nullptr);
    // down: 64x128 split-K2 (320 blocks) + residual in reduce
    convert_w_kernel<<<dim3(54, 20), 256, 0, stream>>>(
        down_w + (size_t)i * 3456 * 1280, WPH, WPL, 3456, 1280, 0, 3456, 0, 1, 0);
    gemm_bf2<64, 128, 0, 2><<<dim3(10, 16, 2), 256, 0, stream>>>(
        DAh, DAl, WPH, WPL, nullptr, nullptr, nullptr, nullptr, 3456, 1280, 1024, PART);
    reduce_k<1><<<1280, 256, 0, stream>>>(PART, 2, 1024, 1280,
        down_b + (size_t)i * 1280, H, H, nullptr, nullptr, nullptr);
  }

  // merger
  rmsnorm_kernel<<<1024, 256, 0, stream>>>(H, lnq_w, ANh, ANl);
  // m1: 256x5120x5120, 64x128 split-K4 (640 blocks), gelu -> planes
  convert_w_kernel<<<dim3(80, 80), 256, 0, stream>>>(m1_w, WPH, WPL, 5120, 5120, 0, 5120, 0, 1, 0);
  gemm_bf2<64, 128, 0, 4><<<dim3(40, 4, 4), 256, 0, stream>>>(
      ANh, ANl, WPH, WPL, nullptr, nullptr, nullptr, nullptr, 5120, 5120, 256, PART);
  reduce_k<2><<<1280, 256, 0, stream>>>(PART, 4, 256, 5120,
      m1_b, nullptr, nullptr, G1h, G1l, nullptr);
  // m2: 256x3584x5120, 64x128 split-K4 (448 blocks), scatter rows
  convert_w_kernel<<<dim3(80, 56), 256, 0, stream>>>(m2_w, WPH, WPL, 5120, 3584, 0, 5120, 0, 1, 0);
  gemm_bf2<64, 128, 0, 4><<<dim3(28, 4, 4), 256, 0, stream>>>(
      G1h, G1l, WPH, WPL, nullptr, nullptr, nullptr, nullptr, 5120, 3584, 256, PART);
  reduce_k<3><<<896, 256, 0, stream>>>(PART, 4, 256, 3584,
      m2_b, nullptr, (float*)d_out, nullptr, nullptr, win);
}

// Round 6
// 1709.973 us; speedup vs baseline: 4.8246x; 1.4771x over previous
//
#include <hip/hip_runtime.h>
#include <math.h>

typedef float  floatx4  __attribute__((ext_vector_type(4)));
typedef short  short8   __attribute__((ext_vector_type(8)));
typedef _Float16 half8  __attribute__((ext_vector_type(8)));
typedef _Float16 half4  __attribute__((ext_vector_type(4)));

// ---------- bf16 helpers (RNE) — used by attention path ----------
__device__ inline unsigned short f2bf(float x){
  unsigned u = __float_as_uint(x);
  u += 0x7FFFu + ((u >> 16) & 1u);
  return (unsigned short)(u >> 16);
}
__device__ inline float bf2f(unsigned short b){ return __uint_as_float(((unsigned)b) << 16); }
__device__ inline void split_bf(float x, unsigned short& h, unsigned short& l){
  h = f2bf(x); l = f2bf(x - bf2f(h));
}

// ---------- MFMA 16x16x32 (bf16 for attention, f16 for GEMMs) ----------
// A-frag: lane l holds A[l&15][(l>>4)*8+j]; B-frag: lane l holds B[(l>>4)*8+j][l&15]
// C/D: lane l reg r = D[(l>>4)*4+r][l&15]   (verified rounds 1-5)
__device__ inline floatx4 mfma_bf(short8 a, short8 b, floatx4 c){
  return __builtin_amdgcn_mfma_f32_16x16x32_bf16(a, b, c, 0, 0, 0);
}
__device__ inline floatx4 mfma_f16(half8 a, half8 b, floatx4 c){
  return __builtin_amdgcn_mfma_f32_16x16x32_f16(a, b, c, 0, 0, 0);
}

// ---------- async global->LDS, 16B per lane ----------
__device__ inline void gld_lds16(const void* g, void* l){
  __builtin_amdgcn_global_load_lds(
      (const __attribute__((address_space(1))) unsigned int*)g,
      (__attribute__((address_space(3))) unsigned int*)l, 16, 0, 0);
}

// =======================================================================
// fp16 GEMM: out[M,N] = A[M,K] @ W^T[N,K], single fp16 plane each.
// Double-buffered LDS, global_load_lds staging, XOR-swizzled granules,
// XCD-chunked block swizzle. Grids tail-free.
// KSPLIT>1: f32 partials to part[(z*Mtot+row)*N+col]; epilogue in reduce_k.
// KSPLIT==1 modes: 0: outf = acc + bias; 4: interleaved gate/up silu->fp16.
// =======================================================================
template<int BM, int BN, int MODE, int KSPLIT>
__global__ __launch_bounds__(256) void gemm_f16(
    const _Float16* __restrict__ A, const _Float16* __restrict__ W,
    const float* __restrict__ bias,
    float* __restrict__ outf, _Float16* __restrict__ outp,
    int K, int Nout, int Mtot, float* __restrict__ part)
{
  __shared__ _Float16 SA[2][BM*32];
  __shared__ _Float16 SW[2][BN*32];
  const int tid = threadIdx.x, lane = tid & 63, wv = tid >> 6;
  const int wm = wv >> 1, wn = wv & 1;

  // ---- XCD-chunked bijective swizzle (requires gx*gy % 8 == 0)
  int m_idx, n_idx;
  {
    const int gx = gridDim.x, gy = gridDim.y;
    const int T = gx * gy;
    int id = blockIdx.y * gx + blockIdx.x;
    if ((T & 7) == 0){
      int wg = (id & 7) * (T >> 3) + (id >> 3);
      n_idx = wg / gy; m_idx = wg - n_idx * gy;
    } else { n_idx = blockIdx.x; m_idx = blockIdx.y; }
  }
  const int m0 = m_idx * BM, n0 = n_idx * BN;
  const int kbase = (KSPLIT > 1) ? blockIdx.z * (K / KSPLIT) : 0;
  constexpr int MR = BM / 32, NR = BN / 32;
  floatx4 acc[MR][NR];
  #pragma unroll
  for (int mr = 0; mr < MR; mr++)
    #pragma unroll
    for (int nr = 0; nr < NR; nr++) acc[mr][nr] = 0.f;
  const int fr = lane & 15, kg = lane >> 4;

  auto stage = [&](int buf, int k0){
    #pragma unroll
    for (int p = 0; p < (BM * 4) / 256; p++){
      int lin = p * 256 + tid;
      int row = lin >> 2, gg = (lin & 3) ^ ((row >> 1) & 3);
      size_t go = (size_t)(m0 + row) * K + kbase + k0 + gg * 8;
      gld_lds16(A + go, &SA[buf][(p * 256 + wv * 64) * 8]);
    }
    #pragma unroll
    for (int p = 0; p < (BN * 4) / 256; p++){
      int lin = p * 256 + tid;
      int row = lin >> 2, gg = (lin & 3) ^ ((row >> 1) & 3);
      size_t go = (size_t)(n0 + row) * K + kbase + k0 + gg * 8;
      gld_lds16(W + go, &SW[buf][(p * 256 + wv * 64) * 8]);
    }
  };

  stage(0, 0);
  __syncthreads();
  const int nt = (K / KSPLIT) >> 5;
  for (int t = 0; t < nt; t++){
    const int buf = t & 1;
    if (t + 1 < nt) stage(buf ^ 1, (t + 1) << 5);
    half8 af[MR], wf[NR];
    #pragma unroll
    for (int mr = 0; mr < MR; mr++){
      int r = wm * (BM / 2) + mr * 16 + fr;
      int off = r * 64 + ((kg ^ ((r >> 1) & 3)) << 4);
      af[mr] = *(const half8*)((const char*)&SA[buf][0] + off);
    }
    #pragma unroll
    for (int nr = 0; nr < NR; nr++){
      int r = wn * (BN / 2) + nr * 16 + fr;
      int off = r * 64 + ((kg ^ ((r >> 1) & 3)) << 4);
      wf[nr] = *(const half8*)((const char*)&SW[buf][0] + off);
    }
    #pragma unroll
    for (int mr = 0; mr < MR; mr++)
      #pragma unroll
      for (int nr = 0; nr < NR; nr++)
        acc[mr][nr] = mfma_f16(af[mr], wf[nr], acc[mr][nr]);
    __syncthreads();
  }
  #pragma unroll
  for (int mr = 0; mr < MR; mr++)
    #pragma unroll
    for (int nr = 0; nr < NR; nr++){
      int np = n0 + wn * (BN / 2) + nr * 16 + fr;
      #pragma unroll
      for (int e = 0; e < 4; e++){
        int row = m0 + wm * (BM / 2) + mr * 16 + kg * 4 + e;
        float v = acc[mr][nr][e];
        if (KSPLIT > 1){
          part[((size_t)blockIdx.z * Mtot + row) * Nout + np] = v;
        } else {
          v += bias ? bias[np] : 0.f;
          if (MODE == 0) outf[(size_t)row * Nout + np] = v;
          if (MODE == 4){
            float pv = __shfl_xor(v, 1);
            if (!(fr & 1)){
              float dv = v / (1.f + __expf(-v)) * pv;
              outp[(size_t)row * (Nout >> 1) + (np >> 1)] = (_Float16)dv;
            }
          }
        }
      }
    }
}

// =======================================================================
// Split-K reduce + epilogue. part[z][M][N] f32, fixed-order sum.
// MODE 0: outf = sum + bias
// MODE 1: outf = sum + bias + res (res may alias outf)
// MODE 2: outp(fp16) = gelu_exact(sum + bias)
// MODE 3: outf[rowmap[row]*N + col] = sum + bias
// =======================================================================
template<int MODE>
__global__ __launch_bounds__(256) void reduce_k(
    const float* __restrict__ part, int Z, int M, int N,
    const float* __restrict__ bias, const float* __restrict__ res,
    float* __restrict__ outf, _Float16* __restrict__ outp,
    const int* __restrict__ rowmap)
{
  int idx4 = (blockIdx.x * 256 + threadIdx.x) * 4;
  if (idx4 >= M * N) return;
  int row = idx4 / N, col = idx4 - row * N;
  floatx4 v = *(const floatx4*)(part + (size_t)row * N + col);
  for (int z = 1; z < Z; z++){
    floatx4 p = *(const floatx4*)(part + ((size_t)z * M + row) * N + col);
    v[0] += p[0]; v[1] += p[1]; v[2] += p[2]; v[3] += p[3];
  }
  if (bias){
    floatx4 b = *(const floatx4*)(bias + col);
    v[0] += b[0]; v[1] += b[1]; v[2] += b[2]; v[3] += b[3];
  }
  if (MODE == 1){
    floatx4 r = *(const floatx4*)(res + (size_t)row * N + col);
    v[0] += r[0]; v[1] += r[1]; v[2] += r[2]; v[3] += r[3];
  }
  if (MODE == 0 || MODE == 1){
    *(floatx4*)(outf + (size_t)row * N + col) = v;
  } else if (MODE == 2){
    half4 h;
    #pragma unroll
    for (int j = 0; j < 4; j++){
      float g = 0.5f * v[j] * (1.f + erff(v[j] * 0.70710678118654752f));
      h[j] = (_Float16)g;
    }
    *(half4*)(outp + (size_t)row * N + col) = h;
  } else if (MODE == 3){
    *(floatx4*)(outf + (size_t)rowmap[row] * N + col) = v;
  }
}

// =======================================================================
// Weight convert: W f32 [K][Nstride] (cols at n_src0) -> transposed fp16
// plane at row (plane_row0 + n*row_mul + row_add), [.][Kpad], zero-pad k>=K
// =======================================================================
__global__ __launch_bounds__(256) void convert_w_kernel(
    const float* __restrict__ W, _Float16* __restrict__ PH,
    int K, int Nstride, int n_src0, int Kpad, int plane_row0,
    int row_mul, int row_add)
{
  __shared__ float T[64][68];
  const int tid = threadIdx.x;
  const int k0 = blockIdx.x * 64, n0 = blockIdx.y * 64;
  const int kr = tid >> 4, nc = (tid & 15) << 2;
  #pragma unroll
  for (int p = 0; p < 4; p++){
    int k = k0 + p * 16 + kr;
    floatx4 v = {0.f, 0.f, 0.f, 0.f};
    if (k < K) v = *(const floatx4*)(W + (size_t)k * Nstride + n_src0 + n0 + nc);
    *(floatx4*)&T[p * 16 + kr][nc] = v;
  }
  __syncthreads();
  const int n = tid >> 2, kc = (tid & 3) << 4;
  half8 h0, h1;
  #pragma unroll
  for (int j = 0; j < 8; j++){
    h0[j] = (_Float16)T[kc + j][n];
    h1[j] = (_Float16)T[kc + 8 + j][n];
  }
  size_t ro = (size_t)(plane_row0 + (n0 + n) * row_mul + row_add) * Kpad + k0 + kc;
  *(half8*)&PH[ro] = h0; *(half8*)&PH[ro + 8] = h1;
}

// =======================================================================
// RMSNorm: f32 row -> fp16 plane. One block per row, D=1280.
// =======================================================================
__global__ __launch_bounds__(256) void rmsnorm_kernel(
    const float* __restrict__ x, const float* __restrict__ w,
    _Float16* __restrict__ y)
{
  const int row = blockIdx.x;
  const float* xr = x + (size_t)row * 1280;
  float ss = 0.f;
  for (int i = threadIdx.x; i < 1280; i += 256){ float v = xr[i]; ss = fmaf(v, v, ss); }
  for (int o = 32; o > 0; o >>= 1) ss += __shfl_down(ss, o);
  __shared__ float wsum[4];
  __shared__ float snorm;
  if ((threadIdx.x & 63) == 0) wsum[threadIdx.x >> 6] = ss;
  __syncthreads();
  if (threadIdx.x == 0){
    float t = wsum[0] + wsum[1] + wsum[2] + wsum[3];
    snorm = 1.0f / sqrtf(t * (1.0f / 1280.0f) + 1e-6f);
  }
  __syncthreads();
  float s = snorm;
  for (int i = threadIdx.x; i < 1280; i += 256)
    y[(size_t)row * 1280 + i] = (_Float16)(xr[i] * s * w[i]);
}

// =======================================================================
// Patch gather (window perm folded) -> fp16 plane [1024][1216]
// =======================================================================
__global__ __launch_bounds__(256) void gather_x_kernel(
    const float* __restrict__ img, const int* __restrict__ win,
    _Float16* __restrict__ Xp)
{
  int idx = blockIdx.x * 256 + threadIdx.x;
  if (idx >= 1024 * 1216) return;
  int s = idx / 1216, f = idx - s * 1216;
  float val = 0.f;
  if (f < 1176){
    int sp = (win[s >> 2] << 2) | (s & 3);
    int i0 = sp >> 6, r = sp & 63;
    int i3 = r >> 2, rr = r & 3, i1 = rr >> 1, i4 = rr & 1;
    int c  = f / 392, f2 = f - c * 392;
    int f3 = f2 % 196;
    int ph = f3 / 14, pw2 = f3 - ph * 14;
    int hp = (i0 * 2 + i1) * 14 + ph, wp = (i3 * 2 + i4) * 14 + pw2;
    val = img[((size_t)c * 448 + hp) * 448 + wp];
  }
  Xp[idx] = (_Float16)val;
}

__global__ __launch_bounds__(256) void rope_tables_kernel(
    const float* __restrict__ rpe, const int* __restrict__ win,
    float* __restrict__ cosb, float* __restrict__ sinb)
{
  int idx = blockIdx.x * 256 + threadIdx.x;
  if (idx >= 1024 * 80) return;
  int s = idx / 80, d = idx - s * 80;
  int src = (win[s >> 2] << 2) | (s & 3);
  float ang = rpe[src * 40 + (d % 40)];
  cosb[idx] = cosf(ang);
  sinb[idx] = sinf(ang);
}

// qkv f32 -> rope'd Q (pre-scaled), K as bf16 hi/lo planes [16][1024][128]
__global__ __launch_bounds__(256) void rope_qk_kernel(
    const float* __restrict__ qkv, const float* __restrict__ cosb, const float* __restrict__ sinb,
    unsigned short* __restrict__ Qh, unsigned short* __restrict__ Ql,
    unsigned short* __restrict__ Kh, unsigned short* __restrict__ Kl)
{
  int idx = blockIdx.x * 256 + threadIdx.x;
  if (idx >= 1024 * 16 * 128) return;
  int s = idx >> 11;
  int rem = idx & 2047;
  int h = rem >> 7, d = rem & 127;
  size_t o = ((size_t)h * 1024 + s) * 128 + d;
  if (d >= 80){ Qh[o] = 0; Ql[o] = 0; Kh[o] = 0; Kl[o] = 0; return; }
  const float* base = qkv + (size_t)s * 3840;
  float qv = base[h * 80 + d], kv = base[1280 + h * 80 + d];
  float qo = (d < 40) ? -base[h * 80 + d + 40] : base[h * 80 + d - 40];
  float ko = (d < 40) ? -base[1280 + h * 80 + d + 40] : base[1280 + h * 80 + d - 40];
  float cc = cosb[s * 80 + d], sn = sinb[s * 80 + d];
  float q = (qv * cc + qo * sn) * 0.11180339887498949f;
  float k = kv * cc + ko * sn;
  unsigned short hh, ll;
  split_bf(q, hh, ll); Qh[o] = hh; Ql[o] = ll;
  split_bf(k, hh, ll); Kh[o] = hh; Kl[o] = ll;
}

// V transpose: qkv f32 -> VT bf16 planes [16][80][1024]
__global__ __launch_bounds__(256) void vt_kernel(
    const float* __restrict__ qkv,
    unsigned short* __restrict__ Vth, unsigned short* __restrict__ Vtl)
{
  __shared__ float T[64][81];
  const int h = blockIdx.y, s0 = blockIdx.x * 64;
  for (int c = threadIdx.x; c < 64 * 80; c += 256){
    int sl = c / 80, d = c - sl * 80;
    T[sl][d] = qkv[(size_t)(s0 + sl) * 3840 + 2560 + h * 80 + d];
  }
  __syncthreads();
  for (int c = threadIdx.x; c < 80 * 64; c += 256){
    int d = c >> 6, sl = c & 63;
    unsigned short hh, ll; split_bf(T[sl][d], hh, ll);
    size_t o = ((size_t)h * 80 + d) * 1024 + s0 + sl;
    Vth[o] = hh; Vtl[o] = ll;
  }
}

// concat gate_b/up_b interleaved -> [8][6912]
__global__ __launch_bounds__(256) void concat_bias_kernel(
    const float* __restrict__ gb, const float* __restrict__ ub, float* __restrict__ out)
{
  int idx = blockIdx.x * 256 + threadIdx.x;
  if (idx >= 8 * 6912) return;
  int l = idx / 6912, j = idx - l * 6912;
  out[idx] = (j & 1) ? ub[l * 3456 + (j >> 1)] : gb[l * 3456 + (j >> 1)];
}

// =======================================================================
// MFMA flash attention (split-bf16). block = (q-tile 64, head), 4 waves,
// KVBLK=32. Emits fp16 plane for proj's A operand.
// =======================================================================
template<bool FULL>
__global__ __launch_bounds__(256) void attn_mfma(
    const unsigned short* __restrict__ Qh, const unsigned short* __restrict__ Ql,
    const unsigned short* __restrict__ Kh, const unsigned short* __restrict__ Kl,
    const unsigned short* __restrict__ Vth, const unsigned short* __restrict__ Vtl,
    _Float16* __restrict__ Op)
{
  __shared__ unsigned short KT[2][2][32 * 128];
  __shared__ unsigned short VS[2][2][80 * 32];
  __shared__ unsigned short PS[2][64 * 40];
  const int tid = threadIdx.x, lane = tid & 63, wv = tid >> 6;
  const int qb = blockIdx.x, h = blockIdx.y;
  const int fr = lane & 15, kg = lane >> 4;

  short8 qfh[3], qfl[3];
  {
    size_t qbase = ((size_t)h * 1024 + qb * 64 + wv * 16 + fr) * 128;
    #pragma unroll
    for (int ks = 0; ks < 3; ks++){
      qfh[ks] = *(const short8*)(Qh + qbase + ks * 32 + kg * 8);
      qfl[ks] = *(const short8*)(Ql + qbase + ks * 32 + kg * 8);
    }
  }
  float m_r[4], l_r[4];
  #pragma unroll
  for (int r = 0; r < 4; r++){ m_r[r] = -3e38f; l_r[r] = 0.f; }
  floatx4 oa[5];
  #pragma unroll
  for (int nb = 0; nb < 5; nb++) oa[nb] = 0.f;

  const int nt  = FULL ? 32 : 2;
  const int kt0 = FULL ? 0 : qb * 2;

  auto stageK = [&](int buf, int kt){
    #pragma unroll
    for (int p = 0; p < 2; p++){
      int lin = p * 256 + tid;
      int row = lin >> 4, gg = (lin & 15) ^ (row & 7);
      size_t go = ((size_t)h * 1024 + kt * 32 + row) * 128 + gg * 8;
      gld_lds16(Kh + go, &KT[buf][0][(p * 256 + wv * 64) * 8]);
      gld_lds16(Kl + go, &KT[buf][1][(p * 256 + wv * 64) * 8]);
    }
    #pragma unroll
    for (int p = 0; p < 2; p++){
      int lin = p * 256 + tid;
      if (lin < 320){
        int row = lin >> 2, gg = (lin & 3) ^ (row & 3);
        size_t go = ((size_t)h * 80 + row) * 1024 + kt * 32 + gg * 8;
        gld_lds16(Vth + go, &VS[buf][0][(p * 256 + wv * 64) * 8]);
        gld_lds16(Vtl + go, &VS[buf][1][(p * 256 + wv * 64) * 8]);
      }
    }
  };

  stageK(0, kt0);
  __syncthreads();
  for (int t = 0; t < nt; t++){
    const int buf = t & 1;
    if (t + 1 < nt) stageK(buf ^ 1, kt0 + t + 1);
    floatx4 accS[2];
    accS[0] = 0.f; accS[1] = 0.f;
    #pragma unroll
    for (int c = 0; c < 2; c++){
      #pragma unroll
      for (int ks = 0; ks < 3; ks++){
        int row = c * 16 + fr;
        int off = row * 256 + ((ks * 64 + kg * 16) ^ ((row & 7) << 4));
        short8 kh_ = *(const short8*)((const char*)&KT[buf][0][0] + off);
        short8 kl_ = *(const short8*)((const char*)&KT[buf][1][0] + off);
        accS[c] = mfma_bf(qfl[ks], kh_, accS[c]);
        accS[c] = mfma_bf(qfh[ks], kl_, accS[c]);
        accS[c] = mfma_bf(qfh[ks], kh_, accS[c]);
      }
    }
    float corr[4], ps_[4];
    #pragma unroll
    for (int r = 0; r < 4; r++){
      float v = fmaxf(accS[0][r], accS[1][r]);
      v = fmaxf(v, __shfl_xor(v, 1)); v = fmaxf(v, __shfl_xor(v, 2));
      v = fmaxf(v, __shfl_xor(v, 4)); v = fmaxf(v, __shfl_xor(v, 8));
      float mn = fmaxf(m_r[r], v);
      corr[r] = __expf(m_r[r] - mn);
      m_r[r] = mn;
      ps_[r] = 0.f;
    }
    #pragma unroll
    for (int c = 0; c < 2; c++)
      #pragma unroll
      for (int r = 0; r < 4; r++){
        float p = __expf(accS[c][r] - m_r[r]);
        ps_[r] += p;
        unsigned short ph, pl; split_bf(p, ph, pl);
        int po = (wv * 16 + kg * 4 + r) * 40 + c * 16 + fr;
        PS[0][po] = ph;
        PS[1][po] = pl;
      }
    #pragma unroll
    for (int r = 0; r < 4; r++){
      float v = ps_[r];
      v += __shfl_xor(v, 1); v += __shfl_xor(v, 2);
      v += __shfl_xor(v, 4); v += __shfl_xor(v, 8);
      l_r[r] = l_r[r] * corr[r] + v;
      #pragma unroll
      for (int nb = 0; nb < 5; nb++) oa[nb][r] *= corr[r];
    }
    {
      int poff = (wv * 16 + fr) * 80 + kg * 16;
      short8 pah = *(const short8*)((const char*)&PS[0][0] + poff);
      short8 pal = *(const short8*)((const char*)&PS[1][0] + poff);
      #pragma unroll
      for (int nb = 0; nb < 5; nb++){
        int row = nb * 16 + fr;
        int off = row * 64 + ((kg * 16) ^ ((row & 3) << 4));
        short8 vh_ = *(const short8*)((const char*)&VS[buf][0][0] + off);
        short8 vl_ = *(const short8*)((const char*)&VS[buf][1][0] + off);
        oa[nb] = mfma_bf(pal, vh_, oa[nb]);
        oa[nb] = mfma_bf(pah, vl_, oa[nb]);
        oa[nb] = mfma_bf(pah, vh_, oa[nb]);
      }
    }
    __syncthreads();
  }
  float linv[4];
  #pragma unroll
  for (int r = 0; r < 4; r++) linv[r] = 1.f / l_r[r];
  #pragma unroll
  for (int nb = 0; nb < 5; nb++)
    #pragma unroll
    for (int r = 0; r < 4; r++){
      float v = oa[nb][r] * linv[r];
      size_t o = (size_t)(qb * 64 + wv * 16 + kg * 4 + r) * 1280 + h * 80 + nb * 16 + fr;
      Op[o] = (_Float16)v;
    }
}

// =======================================================================
extern "C" void kernel_launch(void* const* d_in, const int* in_sizes, int n_in,
                              void* d_out, int out_size, void* d_ws, size_t ws_size,
                              hipStream_t stream)
{
  (void)in_sizes; (void)n_in; (void)out_size;
  const float* images  = (const float*)d_in[0];
  const int*   win     = (const int*)  d_in[1];
  const float* rpe     = (const float*)d_in[3];
  const float* patch_w = (const float*)d_in[6];
  const float* ln1_w   = (const float*)d_in[7];
  const float* ln2_w   = (const float*)d_in[8];
  const float* qkv_w   = (const float*)d_in[9];
  const float* qkv_b   = (const float*)d_in[10];
  const float* proj_w  = (const float*)d_in[11];
  const float* proj_b  = (const float*)d_in[12];
  const float* gate_w  = (const float*)d_in[13];
  const float* gate_b  = (const float*)d_in[14];
  const float* up_w    = (const float*)d_in[15];
  const float* up_b    = (const float*)d_in[16];
  const float* down_w  = (const float*)d_in[17];
  const float* down_b  = (const float*)d_in[18];
  const float* lnq_w   = (const float*)d_in[19];
  const float* m1_w    = (const float*)d_in[20];
  const float* m1_b    = (const float*)d_in[21];
  const float* m2_w    = (const float*)d_in[22];
  const float* m2_b    = (const float*)d_in[23];

  char* ws = (char*)d_ws;
  size_t off = 0;
  auto alloc = [&](size_t b){ size_t o = off; off += (b + 255) & ~(size_t)255; return o; };
  _Float16* WP  = (_Float16*)(ws + alloc(26214400ull * 2));   // 52.4MB (m1 plane)
  float* PART = (float*)(ws + alloc(22020096ull));            // 21MB split-K partials
  _Float16* Xp  = (_Float16*)(ws + alloc(1024ull * 1216 * 2));
  _Float16* ANp = (_Float16*)(ws + alloc(1024ull * 1280 * 2));
  float* H    = (float*)(ws + alloc(1024ull * 1280 * 4));
  float* QKV  = (float*)(ws + alloc(1024ull * 3840 * 4));
  unsigned short* Qph = (unsigned short*)(ws + alloc(16ull * 1024 * 128 * 2));
  unsigned short* Qpl = (unsigned short*)(ws + alloc(16ull * 1024 * 128 * 2));
  unsigned short* Kph = (unsigned short*)(ws + alloc(16ull * 1024 * 128 * 2));
  unsigned short* Kpl = (unsigned short*)(ws + alloc(16ull * 1024 * 128 * 2));
  unsigned short* Vth = (unsigned short*)(ws + alloc(16ull * 80 * 1024 * 2));
  unsigned short* Vtl = (unsigned short*)(ws + alloc(16ull * 80 * 1024 * 2));
  _Float16* Op  = (_Float16*)(ws + alloc(1024ull * 1280 * 2));
  _Float16* DAp = (_Float16*)(ws + alloc(1024ull * 3456 * 2));
  _Float16* G1p = (_Float16*)(ws + alloc(256ull * 5120 * 2));
  float* COSb = (float*)(ws + alloc(1024ull * 80 * 4));
  float* SINb = (float*)(ws + alloc(1024ull * 80 * 4));
  float* BGU  = (float*)(ws + alloc(8ull * 6912 * 4));
  if (off > ws_size) return;

  gather_x_kernel   <<<4864, 256, 0, stream>>>(images, win, Xp);
  rope_tables_kernel<<<320,  256, 0, stream>>>(rpe, win, COSb, SINb);
  concat_bias_kernel<<<216,  256, 0, stream>>>(gate_b, up_b, BGU);

  // patch embed: 64x128 split-K2 (320 blocks)
  convert_w_kernel<<<dim3(19, 20), 256, 0, stream>>>(patch_w, WP, 1176, 1280, 0, 1216, 0, 1, 0);
  gemm_f16<64, 128, 0, 2><<<dim3(10, 16, 2), 256, 0, stream>>>(
      Xp, WP, nullptr, nullptr, nullptr, 1216, 1280, 1024, PART);
  reduce_k<0><<<1280, 256, 0, stream>>>(PART, 2, 1024, 1280, nullptr, nullptr,
      H, nullptr, nullptr);

  for (int i = 0; i < 8; i++){
    rmsnorm_kernel<<<1024, 256, 0, stream>>>(H, ln1_w + (size_t)i * 1280, ANp);
    // qkv: 64x128, no split-K (480 blocks), bias fused
    convert_w_kernel<<<dim3(20, 60), 256, 0, stream>>>(
        qkv_w + (size_t)i * 1280 * 3840, WP, 1280, 3840, 0, 1280, 0, 1, 0);
    gemm_f16<64, 128, 0, 1><<<dim3(30, 16), 256, 0, stream>>>(
        ANp, WP, qkv_b + (size_t)i * 3840, QKV, nullptr, 1280, 3840, 1024, nullptr);
    rope_qk_kernel<<<8192, 256, 0, stream>>>(QKV, COSb, SINb, Qph, Qpl, Kph, Kpl);
    vt_kernel<<<dim3(16, 16), 256, 0, stream>>>(QKV, Vth, Vtl);
    if (i == 3 || i == 7)
      attn_mfma<true ><<<dim3(16, 16), 256, 0, stream>>>(Qph, Qpl, Kph, Kpl, Vth, Vtl, Op);
    else
      attn_mfma<false><<<dim3(16, 16), 256, 0, stream>>>(Qph, Qpl, Kph, Kpl, Vth, Vtl, Op);
    // proj: 64x128 split-K2 (320 blocks) + residual in reduce
    convert_w_kernel<<<dim3(20, 20), 256, 0, stream>>>(
        proj_w + (size_t)i * 1280 * 1280, WP, 1280, 1280, 0, 1280, 0, 1, 0);
    gemm_f16<64, 128, 0, 2><<<dim3(10, 16, 2), 256, 0, stream>>>(
        Op, WP, nullptr, nullptr, nullptr, 1280, 1280, 1024, PART);
    reduce_k<1><<<1280, 256, 0, stream>>>(PART, 2, 1024, 1280,
        proj_b + (size_t)i * 1280, H, H, nullptr, nullptr);
    rmsnorm_kernel<<<1024, 256, 0, stream>>>(H, ln2_w + (size_t)i * 1280, ANp);
    // fused gate+up (interleaved): 64x128 (864 blocks), silu epilogue
    convert_w_kernel<<<dim3(20, 54), 256, 0, stream>>>(
        gate_w + (size_t)i * 1280 * 3456, WP, 1280, 3456, 0, 1280, 0, 2, 0);
    convert_w_kernel<<<dim3(20, 54), 256, 0, stream>>>(
        up_w + (size_t)i * 1280 * 3456, WP, 1280, 3456, 0, 1280, 0, 2, 1);
    gemm_f16<64, 128, 4, 1><<<dim3(54, 16), 256, 0, stream>>>(
        ANp, WP, BGU + (size_t)i * 6912, nullptr, DAp, 1280, 6912, 1024, nullptr);
    // down: 64x128 split-K2 (320 blocks) + residual in reduce
    convert_w_kernel<<<dim3(54, 20), 256, 0, stream>>>(
        down_w + (size_t)i * 3456 * 1280, WP, 3456, 1280, 0, 3456, 0, 1, 0);
    gemm_f16<64, 128, 0, 2><<<dim3(10, 16, 2), 256, 0, stream>>>(
        DAp, WP, nullptr, nullptr, nullptr, 3456, 1280, 1024, PART);
    reduce_k<1><<<1280, 256, 0, stream>>>(PART, 2, 1024, 1280,
        down_b + (size_t)i * 1280, H, H, nullptr, nullptr);
  }

  // merger
  rmsnorm_kernel<<<1024, 256, 0, stream>>>(H, lnq_w, ANp);
  // m1: 256x5120x5120, 64x128 split-K4 (640 blocks), gelu -> fp16 plane
  convert_w_kernel<<<dim3(80, 80), 256, 0, stream>>>(m1_w, WP, 5120, 5120, 0, 5120, 0, 1, 0);
  gemm_f16<64, 128, 0, 4><<<dim3(40, 4, 4), 256, 0, stream>>>(
      ANp, WP, nullptr, nullptr, nullptr, 5120, 5120, 256, PART);
  reduce_k<2><<<1280, 256, 0, stream>>>(PART, 4, 256, 5120,
      m1_b, nullptr, nullptr, G1p, nullptr);
  // m2: 256x3584x5120, 64x128 split-K4 (448 blocks), scatter rows
  convert_w_kernel<<<dim3(80, 56), 256, 0, stream>>>(m2_w, WP, 5120, 3584, 0, 5120, 0, 1, 0);
  gemm_f16<64, 128, 0, 4><<<dim3(28, 4, 4), 256, 0, stream>>>(
      G1p, WP, nullptr, nullptr, nullptr, 5120, 3584, 256, PART);
  reduce_k<3><<<896, 256, 0, stream>>>(PART, 4, 256, 3584,
      m2_b, nullptr, (float*)d_out, nullptr, win);
}